// Round 3
// baseline (3005.848 us; speedup 1.0000x reference)
//
#include <hip/hip_runtime.h>
#include <hip/hip_bf16.h>

typedef float f32x4 __attribute__((ext_vector_type(4)));
typedef unsigned short u16;
typedef unsigned short u16x4 __attribute__((ext_vector_type(4)));
typedef unsigned short u16x8 __attribute__((ext_vector_type(8)));

#define NEG_MAX (-3.4028234663852886e38f)
#define NODE_SCALE 0.125f
#define EDGE_SCALE 0.70710678118654752f

__device__ __forceinline__ float bf2f(u16 u) {
  unsigned int w = ((unsigned int)u) << 16;
  return __builtin_bit_cast(float, w);
}
__device__ __forceinline__ u16 f2bf(float f) {
  unsigned int x = __builtin_bit_cast(unsigned int, f);
  x = x + 0x7FFFu + ((x >> 16) & 1u);
  return (u16)(x >> 16);
}

// ---------------- kernel M: normalize mask to float 0/1 (dtype-robust) ----
__global__ void mask_norm(const unsigned char* __restrict__ mraw,
                          float* __restrict__ mask_f) {
  __shared__ int flags;
  int t = threadIdx.x;
  if (t == 0) flags = 0;
  __syncthreads();
  const unsigned int* mu = (const unsigned int*)mraw;
  int f = 0;
  for (int e = t; e < 512; e += 256) { if (mu[e] > 1u) f |= 1; }
  for (int e = t; e < 2048; e += 256) { if (mraw[e] > 1) f |= 2; }
  if (f) atomicOr(&flags, f);
  __syncthreads();
  int fl = flags;
  for (int e = t; e < 2048; e += 256) {
    float v;
    if (!(fl & 1))      v = (mu[e] != 0u) ? 1.f : 0.f;
    else if (!(fl & 2)) v = (mraw[e] != 0) ? 1.f : 0.f;
    else                v = (((const float*)mraw)[e] != 0.f) ? 1.f : 0.f;
    mask_f[e] = v;
  }
}

// ---------------- kernel A: qkv projection + rotary ----------------------
__global__ __launch_bounds__(256) void qkv_rope(
    const float* __restrict__ node, const float* __restrict__ Wq,
    const float* __restrict__ Wk, const float* __restrict__ Wv,
    float* __restrict__ qw, u16* __restrict__ kwb, u16* __restrict__ vwb) {
  __shared__ __align__(16) float xs[8 * 256];
  int t = threadIdx.x;
  int row0 = blockIdx.x * 8;
#pragma unroll
  for (int p = 0; p < 2; ++p) {
    int f = p * 256 + t;
    *(f32x4*)(&xs[f * 4]) = *(const f32x4*)(node + (size_t)row0 * 256 + f * 4);
  }
  __syncthreads();
  float qa[8], ka[8], va[8];
#pragma unroll
  for (int r = 0; r < 8; ++r) { qa[r] = 0.f; ka[r] = 0.f; va[r] = 0.f; }
  for (int c = 0; c < 256; ++c) {
    float wq = Wq[c * 256 + t];
    float wk = Wk[c * 256 + t];
    float wv = Wv[c * 256 + t];
#pragma unroll
    for (int r = 0; r < 8; ++r) {
      float x = xs[r * 256 + c];
      qa[r] += x * wq; ka[r] += x * wk; va[r] += x * wv;
    }
  }
  int d = t & 31;
  float inv = powf(10000.f, -((float)(2 * (d >> 1)) * (1.f / 32.f)));
  int h = t >> 5;
#pragma unroll
  for (int r = 0; r < 8; ++r) {
    int gr = row0 + r;
    int b = gr >> 10, i = gr & 1023;
    float ang = (float)i * inv;
    float sn, cs;
    sincosf(ang, &sn, &cs);
    float qp = __shfl_xor(qa[r], 1, 64);
    float kp = __shfl_xor(ka[r], 1, 64);
    float qo = (d & 1) ? (qp * sn + qa[r] * cs) : (qa[r] * cs - qp * sn);
    float ko = (d & 1) ? (kp * sn + ka[r] * cs) : (ka[r] * cs - kp * sn);
    int idx = ((b * 8 + h) * 1024 + i) * 32 + d;
    qw[idx] = qo;
    kwb[idx] = f2bf(ko);
    vwb[idx] = f2bf(va[r]);
  }
}

// ---------------- kernel B: fused attention (single pass over edge) ------
__global__ __launch_bounds__(256, 3) void attn_fused(
    const float* __restrict__ edge, const float* __restrict__ qw,
    const u16* __restrict__ kwb, const u16* __restrict__ vwb,
    const float* __restrict__ We, const float* __restrict__ be,
    const float* __restrict__ mask_f, float* __restrict__ rescat) {
  __shared__ __align__(16) float buf[2][4096];  // double-buffered 64x64 f32 tile
  __shared__ __align__(16) float Lg[8][68];     // p values per head (stride 68)
  __shared__ __align__(16) float WesT[8][64];   // We transposed [h][d]
  __shared__ __align__(16) float qs[256];       // q[h][d] for this i
  __shared__ float bes[8], mS[8], sS[8], rS[8];

  int bid = blockIdx.x;
  int xcd = bid & 7, slot = bid >> 3;
  int b = xcd >> 2;
  int i = (xcd & 3) * 256 + slot;
  int t = threadIdx.x;
  int lane = t & 63;
  int wave = __builtin_amdgcn_readfirstlane(t >> 6);

  {
    int h = t >> 5, d = t & 31;
    qs[t] = qw[((b * 8 + h) * 1024 + i) * 32 + d];
  }
#pragma unroll
  for (int p = 0; p < 2; ++p) { int e = p * 256 + t; WesT[e & 7][e >> 3] = We[e]; }
  if (t < 8) { bes[t] = be[t]; mS[t] = NEG_MAX; sS[t] = 0.f; rS[t] = 1.f; }

  float mi = mask_f[b * 1024 + i];
  const float* ebase = edge + ((size_t)(b * 1024 + i)) * (1024 * 64);

  // staging map: thread covers quarter-row (16 floats)
  int jrow = t >> 2, dchunk = t & 3;
  const float* gsrc = ebase + jrow * 64 + dchunk * 16;
  int wsw = jrow & 3;  // ds_write bank stagger

  // prologue: tile 0 -> regs -> buf[0]
  f32x4 st0, st1, st2, st3;
  st0 = __builtin_nontemporal_load((const f32x4*)(gsrc + 0));
  st1 = __builtin_nontemporal_load((const f32x4*)(gsrc + 4));
  st2 = __builtin_nontemporal_load((const f32x4*)(gsrc + 8));
  st3 = __builtin_nontemporal_load((const f32x4*)(gsrc + 12));
  {
    float* wb = &buf[0][jrow * 64 + dchunk * 16];
    f32x4 sv[4] = {st0, st1, st2, st3};
#pragma unroll
    for (int q = 0; q < 4; ++q) {
      int qq = q ^ wsw;
      *(f32x4*)(wb + qq * 4) = sv[qq];
    }
  }
  __syncthreads();

  f32x4 acc_v = {0.f, 0.f, 0.f, 0.f};
  f32x4 acce0 = {0.f, 0.f, 0.f, 0.f}, acce1 = {0.f, 0.f, 0.f, 0.f};

  int h3a = t >> 5, dq3a = (t >> 2) & 7, rep3a = t & 3;   // phase 3a map
  int h3 = t & 7, dg3 = (t >> 3) & 7, jc3 = t >> 6;        // phase 3b map
  int h1 = wave, h2 = wave + 4;
  int sw = lane & 7;

  int cur = 0;
  for (int j0 = 0; j0 < 1024; j0 += 64) {
    // ---- A: issue nontemporal loads for tile t+1 (consumed in E) --------
    bool pf = (j0 + 64) < 1024;
    if (pf) {
      const float* g = gsrc + (size_t)(j0 + 64) * 64;
      st0 = __builtin_nontemporal_load((const f32x4*)(g + 0));
      st1 = __builtin_nontemporal_load((const f32x4*)(g + 4));
      st2 = __builtin_nontemporal_load((const f32x4*)(g + 8));
      st3 = __builtin_nontemporal_load((const f32x4*)(g + 12));
    }
    const float* bufc = &buf[cur][0];

    // ---- B: logits + online softmax (heads h1=wave, h2=wave+4) ----------
    {
      int j = lane;
      const float* rowp = bufc + j * 64;
      float bias1 = 0.f, bias2 = 0.f;
#pragma unroll
      for (int k = 0; k < 16; ++k) {
        int s = (k & 8) | ((k & 7) ^ sw);  // bank-staggered column order
        f32x4 ev = *(const f32x4*)(rowp + s * 4);
        f32x4 wa = *(const f32x4*)(&WesT[h1][s * 4]);
        f32x4 wb = *(const f32x4*)(&WesT[h2][s * 4]);
        bias1 += ev.x * wa.x + ev.y * wa.y + ev.z * wa.z + ev.w * wa.w;
        bias2 += ev.x * wb.x + ev.y * wb.y + ev.z * wb.z + ev.w * wb.w;
      }
      float qk1 = 0.f, qk2 = 0.f;
      const u16* kr1 = kwb + ((size_t)((b * 8 + h1) * 1024 + j0 + j)) * 32;
      const u16* kr2 = kwb + ((size_t)((b * 8 + h2) * 1024 + j0 + j)) * 32;
#pragma unroll
      for (int g = 0; g < 4; ++g) {
        u16x8 k1 = *(const u16x8*)(kr1 + g * 8);
        u16x8 k2 = *(const u16x8*)(kr2 + g * 8);
        f32x4 q1a = *(const f32x4*)(&qs[h1 * 32 + g * 8]);
        f32x4 q1b = *(const f32x4*)(&qs[h1 * 32 + g * 8 + 4]);
        f32x4 q2a = *(const f32x4*)(&qs[h2 * 32 + g * 8]);
        f32x4 q2b = *(const f32x4*)(&qs[h2 * 32 + g * 8 + 4]);
        qk1 += bf2f(k1[0]) * q1a.x + bf2f(k1[1]) * q1a.y + bf2f(k1[2]) * q1a.z + bf2f(k1[3]) * q1a.w
             + bf2f(k1[4]) * q1b.x + bf2f(k1[5]) * q1b.y + bf2f(k1[6]) * q1b.z + bf2f(k1[7]) * q1b.w;
        qk2 += bf2f(k2[0]) * q2a.x + bf2f(k2[1]) * q2a.y + bf2f(k2[2]) * q2a.z + bf2f(k2[3]) * q2a.w
             + bf2f(k2[4]) * q2b.x + bf2f(k2[5]) * q2b.y + bf2f(k2[6]) * q2b.z + bf2f(k2[7]) * q2b.w;
      }
      bool pm = (mi != 0.f) && (mask_f[b * 1024 + j0 + j] != 0.f);
      float l1 = pm ? (NODE_SCALE * qk1 + EDGE_SCALE * (bias1 + bes[h1])) : NEG_MAX;
      float l2 = pm ? (NODE_SCALE * qk2 + EDGE_SCALE * (bias2 + bes[h2])) : NEG_MAX;
      float mx1 = l1, mx2 = l2;
#pragma unroll
      for (int off = 32; off; off >>= 1) {
        mx1 = fmaxf(mx1, __shfl_xor(mx1, off, 64));
        mx2 = fmaxf(mx2, __shfl_xor(mx2, off, 64));
      }
      float mo1 = mS[h1], mo2 = mS[h2];
      float mn1 = fmaxf(mo1, mx1), mn2 = fmaxf(mo2, mx2);
      float p1 = __expf(l1 - mn1), p2 = __expf(l2 - mn2);
      float ps1 = p1, ps2 = p2;
#pragma unroll
      for (int off = 32; off; off >>= 1) {
        ps1 += __shfl_xor(ps1, off, 64);
        ps2 += __shfl_xor(ps2, off, 64);
      }
      Lg[h1][j] = p1;
      Lg[h2][j] = p2;
      if (lane == 0) {
        float r1 = __expf(mo1 - mn1), r2 = __expf(mo2 - mn2);
        rS[h1] = r1; sS[h1] = sS[h1] * r1 + ps1; mS[h1] = mn1;
        rS[h2] = r2; sS[h2] = sS[h2] * r2 + ps2; mS[h2] = mn2;
      }
    }
    // ---- C: LDS-only barrier (nt loads stay in flight) ------------------
    asm volatile("s_waitcnt lgkmcnt(0)" ::: "memory");
    __builtin_amdgcn_s_barrier();

    // ---- D1: acc_v (thread: h3a, d-quad dq3a, j-chunk rep3a) ------------
    {
      float r = rS[h3a];
      const u16* vb = vwb + ((size_t)((b * 8 + h3a) * 1024 + j0 + rep3a * 16)) * 32 + dq3a * 4;
      f32x4 s4 = {0.f, 0.f, 0.f, 0.f};
      const float* pL = &Lg[h3a][rep3a * 16];
#pragma unroll
      for (int x = 0; x < 16; ++x) {
        float p = pL[x];
        u16x4 vv = *(const u16x4*)(vb + (size_t)x * 32);
        s4.x += p * bf2f(vv[0]);
        s4.y += p * bf2f(vv[1]);
        s4.z += p * bf2f(vv[2]);
        s4.w += p * bf2f(vv[3]);
      }
      acc_v = acc_v * r + s4;
    }
    // ---- D2: acc_e (thread: head h3, d-octet dg3, 16 rows jc3*16..) -----
    {
      float r = rS[h3];
      const float* pL = &Lg[h3][jc3 * 16];
      const float* eB = bufc + (jc3 * 16) * 64 + dg3 * 8;
      f32x4 s0 = {0.f, 0.f, 0.f, 0.f}, s1 = {0.f, 0.f, 0.f, 0.f};
#pragma unroll
      for (int x = 0; x < 16; ++x) {
        float p = pL[x];
        f32x4 e0 = *(const f32x4*)(eB + x * 64);
        f32x4 e1 = *(const f32x4*)(eB + x * 64 + 4);
        s0 += e0 * p;
        s1 += e1 * p;
      }
      acce0 = acce0 * r + s0;
      acce1 = acce1 * r + s1;
    }
    // ---- E: write staged regs -> buf[cur^1] ------------------------------
    if (pf) {
      float* wb = &buf[cur ^ 1][jrow * 64 + dchunk * 16];
      f32x4 sv[4] = {st0, st1, st2, st3};
#pragma unroll
      for (int q = 0; q < 4; ++q) {
        int qq = q ^ wsw;
        *(f32x4*)(wb + qq * 4) = sv[qq];
      }
    }
    // ---- F: barrier (staged writes + all reads of bufc complete) --------
    asm volatile("s_waitcnt lgkmcnt(0)" ::: "memory");
    __builtin_amdgcn_s_barrier();
    cur ^= 1;
  }

  // ---- epilogue ----------------------------------------------------------
  float* red = &buf[0][0];
  // acc_v partials at red[0..1023], acc_e partials at red[1024..3071]
  *(f32x4*)(red + t * 4) = acc_v;
  {
    float* ep = red + 1024 + jc3 * 512 + h3 * 64 + dg3 * 8;
    *(f32x4*)(ep) = acce0;
    *(f32x4*)(ep + 4) = acce1;
  }
  __syncthreads();
  {
    int h = t >> 5, d = t & 31, dqq = d >> 2, c = d & 3;
    float sum = 0.f;
#pragma unroll
    for (int rp = 0; rp < 4; ++rp)
      sum += red[(((h << 5) | (dqq << 2) | rp) << 2) + c];
    rescat[((size_t)(b * 1024 + i)) * 768 + h * 32 + d] = sum / sS[h];
  }
  {
    int h = t >> 5, d = t & 31;
    float inv = 1.f / sS[h];
    size_t base = ((size_t)(b * 1024 + i)) * 768 + 256;
#pragma unroll
    for (int half = 0; half < 2; ++half) {
      int dd = d + half * 32;
      float sum = 0.f;
#pragma unroll
      for (int g = 0; g < 4; ++g) sum += red[1024 + g * 512 + h * 64 + dd];
      rescat[base + h * 64 + dd] = sum * inv;
    }
  }
}

// ---------------- kernel C: output projection ----------------------------
__global__ __launch_bounds__(256) void out_proj(
    const float* __restrict__ rescat, const float* __restrict__ Wo,
    const float* __restrict__ bo, float* __restrict__ out) {
  __shared__ __align__(16) float xs[8 * 768];
  int t = threadIdx.x;
  int row0 = blockIdx.x * 8;
#pragma unroll
  for (int p = 0; p < 6; ++p) {
    int f = p * 256 + t;
    *(f32x4*)(&xs[f * 4]) = *(const f32x4*)(rescat + (size_t)row0 * 768 + f * 4);
  }
  __syncthreads();
  float acc[8];
#pragma unroll
  for (int r = 0; r < 8; ++r) acc[r] = 0.f;
  for (int c = 0; c < 768; ++c) {
    float w = Wo[c * 256 + t];
#pragma unroll
    for (int r = 0; r < 8; ++r) acc[r] += xs[r * 768 + c] * w;
  }
  float bias = bo[t];
#pragma unroll
  for (int r = 0; r < 8; ++r)
    out[(size_t)(row0 + r) * 256 + t] = acc[r] + bias;
}

// ---------------- launch ---------------------------------------------------
extern "C" void kernel_launch(void* const* d_in, const int* in_sizes, int n_in,
                              void* d_out, int out_size, void* d_ws, size_t ws_size,
                              hipStream_t stream) {
  const float* node = (const float*)d_in[0];
  const float* edge = (const float*)d_in[1];
  const unsigned char* mask = (const unsigned char*)d_in[2];
  const float* Wq = (const float*)d_in[3];
  const float* Wk = (const float*)d_in[4];
  const float* Wv = (const float*)d_in[5];
  const float* We = (const float*)d_in[6];
  const float* be = (const float*)d_in[7];
  const float* Wo = (const float*)d_in[8];
  const float* bo = (const float*)d_in[9];

  float* ws = (float*)d_ws;
  float* qw = ws;                              // 524288 f32
  u16* kwb = (u16*)(ws + 524288);              // 524288 bf16
  u16* vwb = kwb + 524288;                     // 524288 bf16
  float* rescat = ws + 1048576;                // 1572864 f32
  float* mask_f = ws + 2621440;                // 2048 f32

  hipLaunchKernelGGL(mask_norm, dim3(1), dim3(256), 0, stream, mask, mask_f);
  hipLaunchKernelGGL(qkv_rope, dim3(256), dim3(256), 0, stream,
                     node, Wq, Wk, Wv, qw, kwb, vwb);
  hipLaunchKernelGGL(attn_fused, dim3(2048), dim3(256), 0, stream,
                     edge, qw, kwb, vwb, We, be, mask_f, rescat);
  hipLaunchKernelGGL(out_proj, dim3(256), dim3(256), 0, stream,
                     rescat, Wo, bo, (float*)d_out);
}

// Round 4
// 671.032 us; speedup vs baseline: 4.4794x; 4.4794x over previous
//
#include <hip/hip_runtime.h>
#include <hip/hip_bf16.h>

typedef float f32x4 __attribute__((ext_vector_type(4)));
typedef unsigned short u16;
typedef unsigned short u16x4 __attribute__((ext_vector_type(4)));
typedef unsigned short u16x8 __attribute__((ext_vector_type(8)));

#define NEG_MAX (-3.4028234663852886e38f)
#define NODE_SCALE 0.125f
#define EDGE_SCALE 0.70710678118654752f
#define QSTR 260  // padded quad-slot stride (floats): 64 rows * 4 + 4 pad

__device__ __forceinline__ float bf2f(u16 u) {
  unsigned int w = ((unsigned int)u) << 16;
  return __builtin_bit_cast(float, w);
}
__device__ __forceinline__ u16 f2bf(float f) {
  unsigned int x = __builtin_bit_cast(unsigned int, f);
  x = x + 0x7FFFu + ((x >> 16) & 1u);
  return (u16)(x >> 16);
}

// ---------------- kernel M: normalize mask to float 0/1 (dtype-robust) ----
__global__ void mask_norm(const unsigned char* __restrict__ mraw,
                          float* __restrict__ mask_f) {
  __shared__ int flags;
  int t = threadIdx.x;
  if (t == 0) flags = 0;
  __syncthreads();
  const unsigned int* mu = (const unsigned int*)mraw;
  int f = 0;
  for (int e = t; e < 512; e += 256) { if (mu[e] > 1u) f |= 1; }
  for (int e = t; e < 2048; e += 256) { if (mraw[e] > 1) f |= 2; }
  if (f) atomicOr(&flags, f);
  __syncthreads();
  int fl = flags;
  for (int e = t; e < 2048; e += 256) {
    float v;
    if (!(fl & 1))      v = (mu[e] != 0u) ? 1.f : 0.f;
    else if (!(fl & 2)) v = (mraw[e] != 0) ? 1.f : 0.f;
    else                v = (((const float*)mraw)[e] != 0.f) ? 1.f : 0.f;
    mask_f[e] = v;
  }
}

// ---------------- kernel A: qkv projection + rotary ----------------------
__global__ __launch_bounds__(256) void qkv_rope(
    const float* __restrict__ node, const float* __restrict__ Wq,
    const float* __restrict__ Wk, const float* __restrict__ Wv,
    float* __restrict__ qw, u16* __restrict__ kwb, u16* __restrict__ vwb) {
  __shared__ __align__(16) float xs[8 * 256];
  int t = threadIdx.x;
  int row0 = blockIdx.x * 8;
#pragma unroll
  for (int p = 0; p < 2; ++p) {
    int f = p * 256 + t;
    *(f32x4*)(&xs[f * 4]) = *(const f32x4*)(node + (size_t)row0 * 256 + f * 4);
  }
  __syncthreads();
  float qa[8], ka[8], va[8];
#pragma unroll
  for (int r = 0; r < 8; ++r) { qa[r] = 0.f; ka[r] = 0.f; va[r] = 0.f; }
  for (int c = 0; c < 256; ++c) {
    float wq = Wq[c * 256 + t];
    float wk = Wk[c * 256 + t];
    float wv = Wv[c * 256 + t];
#pragma unroll
    for (int r = 0; r < 8; ++r) {
      float x = xs[r * 256 + c];
      qa[r] += x * wq; ka[r] += x * wk; va[r] += x * wv;
    }
  }
  int d = t & 31;
  float inv = powf(10000.f, -((float)(2 * (d >> 1)) * (1.f / 32.f)));
  int h = t >> 5;
#pragma unroll
  for (int r = 0; r < 8; ++r) {
    int gr = row0 + r;
    int b = gr >> 10, i = gr & 1023;
    float ang = (float)i * inv;
    float sn, cs;
    sincosf(ang, &sn, &cs);
    float qp = __shfl_xor(qa[r], 1, 64);
    float kp = __shfl_xor(ka[r], 1, 64);
    float qo = (d & 1) ? (qp * sn + qa[r] * cs) : (qa[r] * cs - qp * sn);
    float ko = (d & 1) ? (kp * sn + ka[r] * cs) : (ka[r] * cs - kp * sn);
    int idx = ((b * 8 + h) * 1024 + i) * 32 + d;
    qw[idx] = qo;
    kwb[idx] = f2bf(ko);
    vwb[idx] = f2bf(va[r]);
  }
}

// ---------------- kernel B: fused attention (single pass over edge) ------
// buf layout: quad-major. Element (row j, float col c) of the 64x64 tile
// lives at buf[(c>>2)*QSTR + j*4 + (c&3)]. Phase-B reads are contiguous
// 16B/lane (conflict-free b128); staging writes and D2 reads are <=2-way.
__global__ __launch_bounds__(256) void attn_fused(
    const float* __restrict__ edge, const float* __restrict__ qw,
    const u16* __restrict__ kwb, const u16* __restrict__ vwb,
    const float* __restrict__ We, const float* __restrict__ be,
    const float* __restrict__ mask_f, float* __restrict__ rescat) {
  __shared__ __align__(16) float buf[2][16 * QSTR];  // 2 x 16.6 KB
  __shared__ __align__(16) float Lg[8][68];          // p values per head
  __shared__ __align__(16) float WesT[8][64];        // We transposed [h][d]
  __shared__ __align__(16) float qs[256];            // q[h][d] for this i
  __shared__ float bes[8], mS[8], sS[8], rS[8];

  int bid = blockIdx.x;
  int xcd = bid & 7, slot = bid >> 3;
  int b = xcd >> 2;
  int i = (xcd & 3) * 256 + slot;
  int t = threadIdx.x;
  int lane = t & 63;
  int wave = __builtin_amdgcn_readfirstlane(t >> 6);

  {
    int h = t >> 5, d = t & 31;
    qs[t] = qw[((b * 8 + h) * 1024 + i) * 32 + d];
  }
#pragma unroll
  for (int p = 0; p < 2; ++p) { int e = p * 256 + t; WesT[e & 7][e >> 3] = We[e]; }
  if (t < 8) { bes[t] = be[t]; mS[t] = NEG_MAX; sS[t] = 0.f; rS[t] = 1.f; }

  float mi = mask_f[b * 1024 + i];
  const float* ebase = edge + ((size_t)(b * 1024 + i)) * (1024 * 64);

  // staging map: thread covers quarter-row (16 floats = quads dchunk*4..+3)
  int jrow = t >> 2, dchunk = t & 3;
  const float* gsrc = ebase + jrow * 64 + dchunk * 16;
  int woff = (dchunk * 4) * QSTR + jrow * 4;  // LDS write base (float idx)

  // prologue: tile 0 -> regs -> buf[0]
  f32x4 st0, st1, st2, st3;
  st0 = __builtin_nontemporal_load((const f32x4*)(gsrc + 0));
  st1 = __builtin_nontemporal_load((const f32x4*)(gsrc + 4));
  st2 = __builtin_nontemporal_load((const f32x4*)(gsrc + 8));
  st3 = __builtin_nontemporal_load((const f32x4*)(gsrc + 12));
  {
    float* wb = &buf[0][woff];
    *(f32x4*)(wb + 0 * QSTR) = st0;
    *(f32x4*)(wb + 1 * QSTR) = st1;
    *(f32x4*)(wb + 2 * QSTR) = st2;
    *(f32x4*)(wb + 3 * QSTR) = st3;
  }
  __syncthreads();

  f32x4 acc_v = {0.f, 0.f, 0.f, 0.f};
  f32x4 acce0 = {0.f, 0.f, 0.f, 0.f}, acce1 = {0.f, 0.f, 0.f, 0.f};

  int h3a = t >> 5, dq3a = (t >> 2) & 7, rep3a = t & 3;   // D1 map
  int h3 = t & 7, dg3 = (t >> 3) & 7, jc3 = t >> 6;        // D2 map
  int h1 = wave, h2 = wave + 4;

  int cur = 0;
  for (int j0 = 0; j0 < 1024; j0 += 64) {
    // ---- A: issue nontemporal loads for tile t+1 (consumed in E) --------
    bool pf = (j0 + 64) < 1024;
    if (pf) {
      const float* g = gsrc + (size_t)(j0 + 64) * 64;
      st0 = __builtin_nontemporal_load((const f32x4*)(g + 0));
      st1 = __builtin_nontemporal_load((const f32x4*)(g + 4));
      st2 = __builtin_nontemporal_load((const f32x4*)(g + 8));
      st3 = __builtin_nontemporal_load((const f32x4*)(g + 12));
    }
    const float* bufc = &buf[cur][0];

    // ---- B: logits + online softmax (heads h1=wave, h2=wave+4) ----------
    {
      int j = lane;
      const float* rowp = bufc + j * 4;  // + k*QSTR per quad
      float bias1 = 0.f, bias2 = 0.f;
#pragma unroll
      for (int k = 0; k < 16; ++k) {
        f32x4 ev = *(const f32x4*)(rowp + k * QSTR);
        f32x4 wa = *(const f32x4*)(&WesT[h1][k * 4]);
        f32x4 wb = *(const f32x4*)(&WesT[h2][k * 4]);
        bias1 += ev.x * wa.x + ev.y * wa.y + ev.z * wa.z + ev.w * wa.w;
        bias2 += ev.x * wb.x + ev.y * wb.y + ev.z * wb.z + ev.w * wb.w;
      }
      float qk1 = 0.f, qk2 = 0.f;
      const u16* kr1 = kwb + ((size_t)((b * 8 + h1) * 1024 + j0 + j)) * 32;
      const u16* kr2 = kwb + ((size_t)((b * 8 + h2) * 1024 + j0 + j)) * 32;
#pragma unroll
      for (int g = 0; g < 4; ++g) {
        u16x8 k1 = *(const u16x8*)(kr1 + g * 8);
        u16x8 k2 = *(const u16x8*)(kr2 + g * 8);
        f32x4 q1a = *(const f32x4*)(&qs[h1 * 32 + g * 8]);
        f32x4 q1b = *(const f32x4*)(&qs[h1 * 32 + g * 8 + 4]);
        f32x4 q2a = *(const f32x4*)(&qs[h2 * 32 + g * 8]);
        f32x4 q2b = *(const f32x4*)(&qs[h2 * 32 + g * 8 + 4]);
        qk1 += bf2f(k1[0]) * q1a.x + bf2f(k1[1]) * q1a.y + bf2f(k1[2]) * q1a.z + bf2f(k1[3]) * q1a.w
             + bf2f(k1[4]) * q1b.x + bf2f(k1[5]) * q1b.y + bf2f(k1[6]) * q1b.z + bf2f(k1[7]) * q1b.w;
        qk2 += bf2f(k2[0]) * q2a.x + bf2f(k2[1]) * q2a.y + bf2f(k2[2]) * q2a.z + bf2f(k2[3]) * q2a.w
             + bf2f(k2[4]) * q2b.x + bf2f(k2[5]) * q2b.y + bf2f(k2[6]) * q2b.z + bf2f(k2[7]) * q2b.w;
      }
      bool pm = (mi != 0.f) && (mask_f[b * 1024 + j0 + j] != 0.f);
      float l1 = pm ? (NODE_SCALE * qk1 + EDGE_SCALE * (bias1 + bes[h1])) : NEG_MAX;
      float l2 = pm ? (NODE_SCALE * qk2 + EDGE_SCALE * (bias2 + bes[h2])) : NEG_MAX;
      float mx1 = l1, mx2 = l2;
#pragma unroll
      for (int off = 32; off; off >>= 1) {
        mx1 = fmaxf(mx1, __shfl_xor(mx1, off, 64));
        mx2 = fmaxf(mx2, __shfl_xor(mx2, off, 64));
      }
      float mo1 = mS[h1], mo2 = mS[h2];
      float mn1 = fmaxf(mo1, mx1), mn2 = fmaxf(mo2, mx2);
      float p1 = __expf(l1 - mn1), p2 = __expf(l2 - mn2);
      float ps1 = p1, ps2 = p2;
#pragma unroll
      for (int off = 32; off; off >>= 1) {
        ps1 += __shfl_xor(ps1, off, 64);
        ps2 += __shfl_xor(ps2, off, 64);
      }
      Lg[h1][j] = p1;
      Lg[h2][j] = p2;
      if (lane == 0) {
        float r1 = __expf(mo1 - mn1), r2 = __expf(mo2 - mn2);
        rS[h1] = r1; sS[h1] = sS[h1] * r1 + ps1; mS[h1] = mn1;
        rS[h2] = r2; sS[h2] = sS[h2] * r2 + ps2; mS[h2] = mn2;
      }
    }
    // ---- C: LDS-only barrier (nt loads stay in flight) ------------------
    asm volatile("s_waitcnt lgkmcnt(0)" ::: "memory");
    __builtin_amdgcn_s_barrier();

    // ---- D1: acc_v (thread: h3a, d-quad dq3a, j-chunk rep3a) ------------
    {
      float r = rS[h3a];
      const u16* vb = vwb + ((size_t)((b * 8 + h3a) * 1024 + j0 + rep3a * 16)) * 32 + dq3a * 4;
      f32x4 s4 = {0.f, 0.f, 0.f, 0.f};
      const float* pL = &Lg[h3a][rep3a * 16];
#pragma unroll
      for (int x = 0; x < 16; ++x) {
        float p = pL[x];
        u16x4 vv = *(const u16x4*)(vb + (size_t)x * 32);
        s4.x += p * bf2f(vv[0]);
        s4.y += p * bf2f(vv[1]);
        s4.z += p * bf2f(vv[2]);
        s4.w += p * bf2f(vv[3]);
      }
      acc_v = acc_v * r + s4;
    }
    // ---- D2: acc_e (thread: head h3, d-octet dg3, 16 rows jc3*16..) -----
    {
      float r = rS[h3];
      const float* pL = &Lg[h3][jc3 * 16];
      const float* eB = bufc + (dg3 * 2) * QSTR + (jc3 * 16) * 4;
      f32x4 s0 = {0.f, 0.f, 0.f, 0.f}, s1 = {0.f, 0.f, 0.f, 0.f};
#pragma unroll
      for (int x = 0; x < 16; ++x) {
        float p = pL[x];
        f32x4 e0 = *(const f32x4*)(eB + x * 4);
        f32x4 e1 = *(const f32x4*)(eB + QSTR + x * 4);
        s0 += e0 * p;
        s1 += e1 * p;
      }
      acce0 = acce0 * r + s0;
      acce1 = acce1 * r + s1;
    }
    // ---- E: write staged regs -> buf[cur^1] ------------------------------
    if (pf) {
      float* wb = &buf[cur ^ 1][woff];
      *(f32x4*)(wb + 0 * QSTR) = st0;
      *(f32x4*)(wb + 1 * QSTR) = st1;
      *(f32x4*)(wb + 2 * QSTR) = st2;
      *(f32x4*)(wb + 3 * QSTR) = st3;
    }
    // ---- F: barrier (staged writes + all reads of bufc complete) --------
    asm volatile("s_waitcnt lgkmcnt(0)" ::: "memory");
    __builtin_amdgcn_s_barrier();
    cur ^= 1;
  }

  // ---- epilogue ----------------------------------------------------------
  float* red = &buf[0][0];
  // acc_v partials at red[0..1023], acc_e partials at red[1024..3071]
  *(f32x4*)(red + t * 4) = acc_v;
  {
    float* ep = red + 1024 + jc3 * 512 + h3 * 64 + dg3 * 8;
    *(f32x4*)(ep) = acce0;
    *(f32x4*)(ep + 4) = acce1;
  }
  __syncthreads();
  {
    int h = t >> 5, d = t & 31, dqq = d >> 2, c = d & 3;
    float sum = 0.f;
#pragma unroll
    for (int rp = 0; rp < 4; ++rp)
      sum += red[(((h << 5) | (dqq << 2) | rp) << 2) + c];
    rescat[((size_t)(b * 1024 + i)) * 768 + h * 32 + d] = sum / sS[h];
  }
  {
    int h = t >> 5, d = t & 31;
    float inv = 1.f / sS[h];
    size_t base = ((size_t)(b * 1024 + i)) * 768 + 256;
#pragma unroll
    for (int half = 0; half < 2; ++half) {
      int dd = d + half * 32;
      float sum = 0.f;
#pragma unroll
      for (int g = 0; g < 4; ++g) sum += red[1024 + g * 512 + h * 64 + dd];
      rescat[base + h * 64 + dd] = sum * inv;
    }
  }
}

// ---------------- kernel C: output projection ----------------------------
__global__ __launch_bounds__(256) void out_proj(
    const float* __restrict__ rescat, const float* __restrict__ Wo,
    const float* __restrict__ bo, float* __restrict__ out) {
  __shared__ __align__(16) float xs[8 * 768];
  int t = threadIdx.x;
  int row0 = blockIdx.x * 8;
#pragma unroll
  for (int p = 0; p < 6; ++p) {
    int f = p * 256 + t;
    *(f32x4*)(&xs[f * 4]) = *(const f32x4*)(rescat + (size_t)row0 * 768 + f * 4);
  }
  __syncthreads();
  float acc[8];
#pragma unroll
  for (int r = 0; r < 8; ++r) acc[r] = 0.f;
  for (int c = 0; c < 768; ++c) {
    float w = Wo[c * 256 + t];
#pragma unroll
    for (int r = 0; r < 8; ++r) acc[r] += xs[r * 768 + c] * w;
  }
  float bias = bo[t];
#pragma unroll
  for (int r = 0; r < 8; ++r)
    out[(size_t)(row0 + r) * 256 + t] = acc[r] + bias;
}

// ---------------- launch ---------------------------------------------------
extern "C" void kernel_launch(void* const* d_in, const int* in_sizes, int n_in,
                              void* d_out, int out_size, void* d_ws, size_t ws_size,
                              hipStream_t stream) {
  const float* node = (const float*)d_in[0];
  const float* edge = (const float*)d_in[1];
  const unsigned char* mask = (const unsigned char*)d_in[2];
  const float* Wq = (const float*)d_in[3];
  const float* Wk = (const float*)d_in[4];
  const float* Wv = (const float*)d_in[5];
  const float* We = (const float*)d_in[6];
  const float* be = (const float*)d_in[7];
  const float* Wo = (const float*)d_in[8];
  const float* bo = (const float*)d_in[9];

  float* ws = (float*)d_ws;
  float* qw = ws;                              // 524288 f32
  u16* kwb = (u16*)(ws + 524288);              // 524288 bf16
  u16* vwb = kwb + 524288;                     // 524288 bf16
  float* rescat = ws + 1048576;                // 1572864 f32
  float* mask_f = ws + 2621440;                // 2048 f32

  hipLaunchKernelGGL(mask_norm, dim3(1), dim3(256), 0, stream, mask, mask_f);
  hipLaunchKernelGGL(qkv_rope, dim3(256), dim3(256), 0, stream,
                     node, Wq, Wk, Wv, qw, kwb, vwb);
  hipLaunchKernelGGL(attn_fused, dim3(2048), dim3(256), 0, stream,
                     edge, qw, kwb, vwb, We, be, mask_f, rescat);
  hipLaunchKernelGGL(out_proj, dim3(256), dim3(256), 0, stream,
                     rescat, Wo, bo, (float*)d_out);
}

// Round 5
// 554.072 us; speedup vs baseline: 5.4250x; 1.2111x over previous
//
#include <hip/hip_runtime.h>
#include <hip/hip_bf16.h>

typedef float f32x4 __attribute__((ext_vector_type(4)));
typedef short short8 __attribute__((ext_vector_type(8)));
typedef unsigned short u16;
typedef unsigned short u16x4 __attribute__((ext_vector_type(4)));
typedef unsigned short u16x8 __attribute__((ext_vector_type(8)));

#define NEG_MAX (-3.4028234663852886e38f)
#define NODE_SCALE 0.125f
#define EDGE_SCALE 0.70710678118654752f
#define ESTR 72  // halfs per row of E tile (16B-aligned rows, bank-uniform)

__device__ __forceinline__ float bf2f(u16 u) {
  unsigned int w = ((unsigned int)u) << 16;
  return __builtin_bit_cast(float, w);
}
__device__ __forceinline__ u16 f2bf(float f) {
  unsigned int x = __builtin_bit_cast(unsigned int, f);
  x = x + 0x7FFFu + ((x >> 16) & 1u);
  return (u16)(x >> 16);
}

// ---------------- kernel M: normalize mask to float 0/1 (dtype-robust) ----
__global__ void mask_norm(const unsigned char* __restrict__ mraw,
                          float* __restrict__ mask_f) {
  __shared__ int flags;
  int t = threadIdx.x;
  if (t == 0) flags = 0;
  __syncthreads();
  const unsigned int* mu = (const unsigned int*)mraw;
  int f = 0;
  for (int e = t; e < 512; e += 256) { if (mu[e] > 1u) f |= 1; }
  for (int e = t; e < 2048; e += 256) { if (mraw[e] > 1) f |= 2; }
  if (f) atomicOr(&flags, f);
  __syncthreads();
  int fl = flags;
  for (int e = t; e < 2048; e += 256) {
    float v;
    if (!(fl & 1))      v = (mu[e] != 0u) ? 1.f : 0.f;
    else if (!(fl & 2)) v = (mraw[e] != 0) ? 1.f : 0.f;
    else                v = (((const float*)mraw)[e] != 0.f) ? 1.f : 0.f;
    mask_f[e] = v;
  }
}

// ---------------- kernel A: qkv projection + rotary ----------------------
__global__ __launch_bounds__(256) void qkv_rope(
    const float* __restrict__ node, const float* __restrict__ Wq,
    const float* __restrict__ Wk, const float* __restrict__ Wv,
    float* __restrict__ qw, u16* __restrict__ kwb, u16* __restrict__ vwb) {
  __shared__ __align__(16) float xs[8 * 256];
  int t = threadIdx.x;
  int row0 = blockIdx.x * 8;
#pragma unroll
  for (int p = 0; p < 2; ++p) {
    int f = p * 256 + t;
    *(f32x4*)(&xs[f * 4]) = *(const f32x4*)(node + (size_t)row0 * 256 + f * 4);
  }
  __syncthreads();
  float qa[8], ka[8], va[8];
#pragma unroll
  for (int r = 0; r < 8; ++r) { qa[r] = 0.f; ka[r] = 0.f; va[r] = 0.f; }
  for (int c = 0; c < 256; ++c) {
    float wq = Wq[c * 256 + t];
    float wk = Wk[c * 256 + t];
    float wv = Wv[c * 256 + t];
#pragma unroll
    for (int r = 0; r < 8; ++r) {
      float x = xs[r * 256 + c];
      qa[r] += x * wq; ka[r] += x * wk; va[r] += x * wv;
    }
  }
  int d = t & 31;
  float inv = powf(10000.f, -((float)(2 * (d >> 1)) * (1.f / 32.f)));
  int h = t >> 5;
#pragma unroll
  for (int r = 0; r < 8; ++r) {
    int gr = row0 + r;
    int b = gr >> 10, i = gr & 1023;
    float ang = (float)i * inv;
    float sn, cs;
    sincosf(ang, &sn, &cs);
    float qp = __shfl_xor(qa[r], 1, 64);
    float kp = __shfl_xor(ka[r], 1, 64);
    float qo = (d & 1) ? (qp * sn + qa[r] * cs) : (qa[r] * cs - qp * sn);
    float ko = (d & 1) ? (kp * sn + ka[r] * cs) : (ka[r] * cs - kp * sn);
    int idx = ((b * 8 + h) * 1024 + i) * 32 + d;
    qw[idx] = qo;
    kwb[idx] = f2bf(ko);
    vwb[idx] = f2bf(va[r]);
  }
}

// ---------------- kernel B: fused attention (single pass over edge) ------
__global__ __launch_bounds__(256) void attn_fused(
    const float* __restrict__ edge, const float* __restrict__ qw,
    const u16* __restrict__ kwb, const u16* __restrict__ vwb,
    const float* __restrict__ We, const float* __restrict__ be,
    const float* __restrict__ mask_f, float* __restrict__ rescat) {
  __shared__ __align__(16) u16 Ejd[2][64 * ESTR];  // bf16 edge tile, dbuf, 18.4KB
  __shared__ __align__(16) float Lg[8][68];        // bias -> p per head
  __shared__ __align__(16) float qs[256];          // q[h][d] for this i
  __shared__ float bes[8], mS[8], sS[8], rS[8];

  int bid = blockIdx.x;
  int xcd = bid & 7, slot = bid >> 3;
  int b = xcd >> 2;
  int i = (xcd & 3) * 256 + slot;
  int t = threadIdx.x;
  int lane = t & 63;
  int wave = __builtin_amdgcn_readfirstlane(t >> 6);

  {
    int h = t >> 5, d = t & 31;
    qs[t] = qw[((b * 8 + h) * 1024 + i) * 32 + d];
  }
  if (t < 8) { bes[t] = be[t] * EDGE_SCALE; mS[t] = NEG_MAX; sS[t] = 0.f; rS[t] = 1.f; }

  // We^T A-fragments (pre-scaled, zero-padded rows h>=8), built once
  short8 weA0, weA1;
  {
    int hh = lane & 15, g = lane >> 4;
#pragma unroll
    for (int e = 0; e < 8; ++e) {
      int d0 = g * 8 + e;
      float w0 = (hh < 8) ? We[d0 * 8 + hh] * EDGE_SCALE : 0.f;
      float w1 = (hh < 8) ? We[(d0 + 32) * 8 + hh] * EDGE_SCALE : 0.f;
      weA0[e] = (short)f2bf(w0);
      weA1[e] = (short)f2bf(w1);
    }
  }

  float mi = mask_f[b * 1024 + i];
  const float* ebase = edge + ((size_t)(b * 1024 + i)) * (1024 * 64);

  // staging map: thread covers quarter-row (16 floats -> 16 bf16)
  int jrow = t >> 2, c4 = t & 3;
  const float* gsrc = ebase + jrow * 64 + c4 * 16;
  int woff = jrow * ESTR + c4 * 16;  // half index within a buffer

  // prologue: tile 0 -> regs -> bf16 -> Ejd[0]
  f32x4 st0, st1, st2, st3;
  st0 = __builtin_nontemporal_load((const f32x4*)(gsrc + 0));
  st1 = __builtin_nontemporal_load((const f32x4*)(gsrc + 4));
  st2 = __builtin_nontemporal_load((const f32x4*)(gsrc + 8));
  st3 = __builtin_nontemporal_load((const f32x4*)(gsrc + 12));
  {
    u16x8 ha, hb;
    ha[0] = f2bf(st0.x); ha[1] = f2bf(st0.y); ha[2] = f2bf(st0.z); ha[3] = f2bf(st0.w);
    ha[4] = f2bf(st1.x); ha[5] = f2bf(st1.y); ha[6] = f2bf(st1.z); ha[7] = f2bf(st1.w);
    hb[0] = f2bf(st2.x); hb[1] = f2bf(st2.y); hb[2] = f2bf(st2.z); hb[3] = f2bf(st2.w);
    hb[4] = f2bf(st3.x); hb[5] = f2bf(st3.y); hb[6] = f2bf(st3.z); hb[7] = f2bf(st3.w);
    *(u16x8*)(&Ejd[0][woff]) = ha;
    *(u16x8*)(&Ejd[0][woff + 8]) = hb;
  }
  __syncthreads();

  f32x4 acc_v = {0.f, 0.f, 0.f, 0.f};
  f32x4 acce0 = {0.f, 0.f, 0.f, 0.f}, acce1 = {0.f, 0.f, 0.f, 0.f};

  int h3a = t >> 5, dq3a = (t >> 2) & 7, rep3a = t & 3;  // PV map
  int h3 = t & 7, dg3 = (t >> 3) & 7, jc3 = t >> 6;       // PE map
  int h1 = wave, h2 = wave + 4;

  int cur = 0;
  for (int j0 = 0; j0 < 1024; j0 += 64) {
    // ---- A: issue nontemporal loads for tile t+1 -------------------------
    bool pf = (j0 + 64) < 1024;
    if (pf) {
      const float* g = gsrc + (size_t)(j0 + 64) * 64;
      st0 = __builtin_nontemporal_load((const f32x4*)(g + 0));
      st1 = __builtin_nontemporal_load((const f32x4*)(g + 4));
      st2 = __builtin_nontemporal_load((const f32x4*)(g + 8));
      st3 = __builtin_nontemporal_load((const f32x4*)(g + 12));
    }
    const u16* Ecur = &Ejd[cur][0];

    // ---- B1: edge bias via MFMA (bias^T[h,j], this wave's 16-j chunk) ----
    {
      const u16* rowp = Ecur + (16 * wave + (lane & 15)) * ESTR + (lane >> 4) * 8;
      short8 bf0 = *(const short8*)(rowp);
      short8 bf1 = *(const short8*)(rowp + 32);
      f32x4 bacc = {0.f, 0.f, 0.f, 0.f};
      bacc = __builtin_amdgcn_mfma_f32_16x16x32_bf16(weA0, bf0, bacc, 0, 0, 0);
      bacc = __builtin_amdgcn_mfma_f32_16x16x32_bf16(weA1, bf1, bacc, 0, 0, 0);
      if (lane < 32) {
        int hb = (lane >> 4) * 4;
        int jc = 16 * wave + (lane & 15);
        Lg[hb + 0][jc] = bacc[0];
        Lg[hb + 1][jc] = bacc[1];
        Lg[hb + 2][jc] = bacc[2];
        Lg[hb + 3][jc] = bacc[3];
      }
    }

    // ---- B2: QK logits (VALU, heads h1/h2, j = lane) ---------------------
    float qk1 = 0.f, qk2 = 0.f;
    {
      int j = lane;
      const u16* kr1 = kwb + ((size_t)((b * 8 + h1) * 1024 + j0 + j)) * 32;
      const u16* kr2 = kwb + ((size_t)((b * 8 + h2) * 1024 + j0 + j)) * 32;
#pragma unroll
      for (int g = 0; g < 4; ++g) {
        u16x8 k1 = *(const u16x8*)(kr1 + g * 8);
        u16x8 k2 = *(const u16x8*)(kr2 + g * 8);
        f32x4 q1a = *(const f32x4*)(&qs[h1 * 32 + g * 8]);
        f32x4 q1b = *(const f32x4*)(&qs[h1 * 32 + g * 8 + 4]);
        f32x4 q2a = *(const f32x4*)(&qs[h2 * 32 + g * 8]);
        f32x4 q2b = *(const f32x4*)(&qs[h2 * 32 + g * 8 + 4]);
        qk1 += bf2f(k1[0]) * q1a.x + bf2f(k1[1]) * q1a.y + bf2f(k1[2]) * q1a.z + bf2f(k1[3]) * q1a.w
             + bf2f(k1[4]) * q1b.x + bf2f(k1[5]) * q1b.y + bf2f(k1[6]) * q1b.z + bf2f(k1[7]) * q1b.w;
        qk2 += bf2f(k2[0]) * q2a.x + bf2f(k2[1]) * q2a.y + bf2f(k2[2]) * q2a.z + bf2f(k2[3]) * q2a.w
             + bf2f(k2[4]) * q2b.x + bf2f(k2[5]) * q2b.y + bf2f(k2[6]) * q2b.z + bf2f(k2[7]) * q2b.w;
      }
    }
    asm volatile("s_waitcnt lgkmcnt(0)" ::: "memory");
    __builtin_amdgcn_s_barrier();

    // ---- S: online softmax (heads h1/h2, j = lane) -----------------------
    {
      int j = lane;
      float bias1 = Lg[h1][j], bias2 = Lg[h2][j];
      bool pm = (mi != 0.f) && (mask_f[b * 1024 + j0 + j] != 0.f);
      float l1 = pm ? (NODE_SCALE * qk1 + bias1 + bes[h1]) : NEG_MAX;
      float l2 = pm ? (NODE_SCALE * qk2 + bias2 + bes[h2]) : NEG_MAX;
      float mx1 = l1, mx2 = l2;
#pragma unroll
      for (int off = 32; off; off >>= 1) {
        mx1 = fmaxf(mx1, __shfl_xor(mx1, off, 64));
        mx2 = fmaxf(mx2, __shfl_xor(mx2, off, 64));
      }
      float mo1 = mS[h1], mo2 = mS[h2];
      float mn1 = fmaxf(mo1, mx1), mn2 = fmaxf(mo2, mx2);
      float p1 = __expf(l1 - mn1), p2 = __expf(l2 - mn2);
      float ps1 = p1, ps2 = p2;
#pragma unroll
      for (int off = 32; off; off >>= 1) {
        ps1 += __shfl_xor(ps1, off, 64);
        ps2 += __shfl_xor(ps2, off, 64);
      }
      Lg[h1][j] = p1;
      Lg[h2][j] = p2;
      if (lane == 0) {
        float r1 = __expf(mo1 - mn1), r2 = __expf(mo2 - mn2);
        rS[h1] = r1; sS[h1] = sS[h1] * r1 + ps1; mS[h1] = mn1;
        rS[h2] = r2; sS[h2] = sS[h2] * r2 + ps2; mS[h2] = mn2;
      }
    }
    asm volatile("s_waitcnt lgkmcnt(0)" ::: "memory");
    __builtin_amdgcn_s_barrier();

    // ---- D0: write staged regs -> Ejd[cur^1] -----------------------------
    if (pf) {
      u16x8 ha, hb;
      ha[0] = f2bf(st0.x); ha[1] = f2bf(st0.y); ha[2] = f2bf(st0.z); ha[3] = f2bf(st0.w);
      ha[4] = f2bf(st1.x); ha[5] = f2bf(st1.y); ha[6] = f2bf(st1.z); ha[7] = f2bf(st1.w);
      hb[0] = f2bf(st2.x); hb[1] = f2bf(st2.y); hb[2] = f2bf(st2.z); hb[3] = f2bf(st2.w);
      hb[4] = f2bf(st3.x); hb[5] = f2bf(st3.y); hb[6] = f2bf(st3.z); hb[7] = f2bf(st3.w);
      *(u16x8*)(&Ejd[cur ^ 1][woff]) = ha;
      *(u16x8*)(&Ejd[cur ^ 1][woff + 8]) = hb;
    }

    // ---- D1: acc_v (PV; thread: h3a, d-quad dq3a, j-chunk rep3a) ---------
    {
      float r = rS[h3a];
      const u16* vb = vwb + ((size_t)((b * 8 + h3a) * 1024 + j0 + rep3a * 16)) * 32 + dq3a * 4;
      float pv[16];
      *(f32x4*)(&pv[0])  = *(const f32x4*)(&Lg[h3a][rep3a * 16 + 0]);
      *(f32x4*)(&pv[4])  = *(const f32x4*)(&Lg[h3a][rep3a * 16 + 4]);
      *(f32x4*)(&pv[8])  = *(const f32x4*)(&Lg[h3a][rep3a * 16 + 8]);
      *(f32x4*)(&pv[12]) = *(const f32x4*)(&Lg[h3a][rep3a * 16 + 12]);
      f32x4 s4 = {0.f, 0.f, 0.f, 0.f};
#pragma unroll
      for (int x = 0; x < 16; ++x) {
        float p = pv[x];
        u16x4 vv = *(const u16x4*)(vb + (size_t)x * 32);
        s4.x += p * bf2f(vv[0]);
        s4.y += p * bf2f(vv[1]);
        s4.z += p * bf2f(vv[2]);
        s4.w += p * bf2f(vv[3]);
      }
      acc_v = acc_v * r + s4;
    }
    // ---- D2: acc_e (PE; thread: head h3, d-octet dg3, 16 rows jc3) -------
    {
      float r = rS[h3];
      float pv[16];
      *(f32x4*)(&pv[0])  = *(const f32x4*)(&Lg[h3][jc3 * 16 + 0]);
      *(f32x4*)(&pv[4])  = *(const f32x4*)(&Lg[h3][jc3 * 16 + 4]);
      *(f32x4*)(&pv[8])  = *(const f32x4*)(&Lg[h3][jc3 * 16 + 8]);
      *(f32x4*)(&pv[12]) = *(const f32x4*)(&Lg[h3][jc3 * 16 + 12]);
      const u16* eB = Ecur + (jc3 * 16) * ESTR + dg3 * 8;
      f32x4 s0 = {0.f, 0.f, 0.f, 0.f}, s1 = {0.f, 0.f, 0.f, 0.f};
#pragma unroll
      for (int x = 0; x < 16; ++x) {
        float p = pv[x];
        u16x8 ev = *(const u16x8*)(eB + x * ESTR);
        s0.x += p * bf2f(ev[0]);
        s0.y += p * bf2f(ev[1]);
        s0.z += p * bf2f(ev[2]);
        s0.w += p * bf2f(ev[3]);
        s1.x += p * bf2f(ev[4]);
        s1.y += p * bf2f(ev[5]);
        s1.z += p * bf2f(ev[6]);
        s1.w += p * bf2f(ev[7]);
      }
      acce0 = acce0 * r + s0;
      acce1 = acce1 * r + s1;
    }
    asm volatile("s_waitcnt lgkmcnt(0)" ::: "memory");
    __builtin_amdgcn_s_barrier();
    cur ^= 1;
  }

  // ---- epilogue ----------------------------------------------------------
  float* red = (float*)&Ejd[0][0];  // 4608 floats of scratch
  *(f32x4*)(red + t * 4) = acc_v;
  {
    float* ep = red + 1024 + jc3 * 512 + h3 * 64 + dg3 * 8;
    *(f32x4*)(ep) = acce0;
    *(f32x4*)(ep + 4) = acce1;
  }
  __syncthreads();
  {
    int h = t >> 5, d = t & 31, dqq = d >> 2, c = d & 3;
    float sum = 0.f;
#pragma unroll
    for (int rp = 0; rp < 4; ++rp)
      sum += red[(((h << 5) | (dqq << 2) | rp) << 2) + c];
    rescat[((size_t)(b * 1024 + i)) * 768 + h * 32 + d] = sum / sS[h];
  }
  {
    int h = t >> 5, d = t & 31;
    float inv = 1.f / sS[h];
    size_t base = ((size_t)(b * 1024 + i)) * 768 + 256;
#pragma unroll
    for (int half = 0; half < 2; ++half) {
      int dd = d + half * 32;
      float sum = 0.f;
#pragma unroll
      for (int g = 0; g < 4; ++g) sum += red[1024 + g * 512 + h * 64 + dd];
      rescat[base + h * 64 + dd] = sum * inv;
    }
  }
}

// ---------------- kernel C: output projection ----------------------------
__global__ __launch_bounds__(256) void out_proj(
    const float* __restrict__ rescat, const float* __restrict__ Wo,
    const float* __restrict__ bo, float* __restrict__ out) {
  __shared__ __align__(16) float xs[8 * 768];
  int t = threadIdx.x;
  int row0 = blockIdx.x * 8;
#pragma unroll
  for (int p = 0; p < 6; ++p) {
    int f = p * 256 + t;
    *(f32x4*)(&xs[f * 4]) = *(const f32x4*)(rescat + (size_t)row0 * 768 + f * 4);
  }
  __syncthreads();
  float acc[8];
#pragma unroll
  for (int r = 0; r < 8; ++r) acc[r] = 0.f;
  for (int c = 0; c < 768; ++c) {
    float w = Wo[c * 256 + t];
#pragma unroll
    for (int r = 0; r < 8; ++r) acc[r] += xs[r * 768 + c] * w;
  }
  float bias = bo[t];
#pragma unroll
  for (int r = 0; r < 8; ++r)
    out[(size_t)(row0 + r) * 256 + t] = acc[r] + bias;
}

// ---------------- launch ---------------------------------------------------
extern "C" void kernel_launch(void* const* d_in, const int* in_sizes, int n_in,
                              void* d_out, int out_size, void* d_ws, size_t ws_size,
                              hipStream_t stream) {
  const float* node = (const float*)d_in[0];
  const float* edge = (const float*)d_in[1];
  const unsigned char* mask = (const unsigned char*)d_in[2];
  const float* Wq = (const float*)d_in[3];
  const float* Wk = (const float*)d_in[4];
  const float* Wv = (const float*)d_in[5];
  const float* We = (const float*)d_in[6];
  const float* be = (const float*)d_in[7];
  const float* Wo = (const float*)d_in[8];
  const float* bo = (const float*)d_in[9];

  float* ws = (float*)d_ws;
  float* qw = ws;                              // 524288 f32
  u16* kwb = (u16*)(ws + 524288);              // 524288 bf16
  u16* vwb = kwb + 524288;                     // 524288 bf16
  float* rescat = ws + 1048576;                // 1572864 f32
  float* mask_f = ws + 2621440;                // 2048 f32

  hipLaunchKernelGGL(mask_norm, dim3(1), dim3(256), 0, stream, mask, mask_f);
  hipLaunchKernelGGL(qkv_rope, dim3(256), dim3(256), 0, stream,
                     node, Wq, Wk, Wv, qw, kwb, vwb);
  hipLaunchKernelGGL(attn_fused, dim3(2048), dim3(256), 0, stream,
                     edge, qw, kwb, vwb, We, be, mask_f, rescat);
  hipLaunchKernelGGL(out_proj, dim3(256), dim3(256), 0, stream,
                     rescat, Wo, bo, (float*)d_out);
}

// Round 6
// 405.445 us; speedup vs baseline: 7.4137x; 1.3666x over previous
//
#include <hip/hip_runtime.h>
#include <hip/hip_bf16.h>

typedef float f32x4 __attribute__((ext_vector_type(4)));
typedef short short8 __attribute__((ext_vector_type(8)));
typedef unsigned short u16;
typedef unsigned int u32;
typedef unsigned int u32x4 __attribute__((ext_vector_type(4)));
typedef unsigned short u16x8 __attribute__((ext_vector_type(8)));

#define NEG_MAX (-3.4028234663852886e38f)
#define NODE_SCALE 0.125f
#define EDGE_SCALE 0.70710678118654752f
#define ESTR 72  // halfs per E-tile row (144B, 16B-aligned, 4-bank row stride)

__device__ __forceinline__ float bf2f(u16 u) {
  unsigned int w = ((unsigned int)u) << 16;
  return __builtin_bit_cast(float, w);
}
__device__ __forceinline__ u16 f2bf(float f) {
  unsigned int x = __builtin_bit_cast(unsigned int, f);
  x = x + 0x7FFFu + ((x >> 16) & 1u);
  return (u16)(x >> 16);
}
__device__ __forceinline__ float asf(u32 x) { return __builtin_bit_cast(float, x); }
__device__ __forceinline__ u32 cvtpk(float lo, float hi) {
  u32 r;
  asm("v_cvt_pk_bf16_f32 %0, %1, %2" : "=v"(r) : "v"(lo), "v"(hi));
  return r;
}

// ---------------- kernel M: normalize mask to float 0/1 (dtype-robust) ----
__global__ void mask_norm(const unsigned char* __restrict__ mraw,
                          float* __restrict__ mask_f) {
  __shared__ int flags;
  int t = threadIdx.x;
  if (t == 0) flags = 0;
  __syncthreads();
  const unsigned int* mu = (const unsigned int*)mraw;
  int f = 0;
  for (int e = t; e < 512; e += 256) { if (mu[e] > 1u) f |= 1; }
  for (int e = t; e < 2048; e += 256) { if (mraw[e] > 1) f |= 2; }
  if (f) atomicOr(&flags, f);
  __syncthreads();
  int fl = flags;
  for (int e = t; e < 2048; e += 256) {
    float v;
    if (!(fl & 1))      v = (mu[e] != 0u) ? 1.f : 0.f;
    else if (!(fl & 2)) v = (mraw[e] != 0) ? 1.f : 0.f;
    else                v = (((const float*)mraw)[e] != 0.f) ? 1.f : 0.f;
    mask_f[e] = v;
  }
}

// ---------------- kernel A: qkv projection + rotary ----------------------
__global__ __launch_bounds__(256) void qkv_rope(
    const float* __restrict__ node, const float* __restrict__ Wq,
    const float* __restrict__ Wk, const float* __restrict__ Wv,
    float* __restrict__ qw, u16* __restrict__ kwb, u16* __restrict__ vwb) {
  __shared__ __align__(16) float xs[8 * 256];
  int t = threadIdx.x;
  int row0 = blockIdx.x * 8;
#pragma unroll
  for (int p = 0; p < 2; ++p) {
    int f = p * 256 + t;
    *(f32x4*)(&xs[f * 4]) = *(const f32x4*)(node + (size_t)row0 * 256 + f * 4);
  }
  __syncthreads();
  float qa[8], ka[8], va[8];
#pragma unroll
  for (int r = 0; r < 8; ++r) { qa[r] = 0.f; ka[r] = 0.f; va[r] = 0.f; }
  for (int c = 0; c < 256; ++c) {
    float wq = Wq[c * 256 + t];
    float wk = Wk[c * 256 + t];
    float wv = Wv[c * 256 + t];
#pragma unroll
    for (int r = 0; r < 8; ++r) {
      float x = xs[r * 256 + c];
      qa[r] += x * wq; ka[r] += x * wk; va[r] += x * wv;
    }
  }
  int d = t & 31;
  float inv = powf(10000.f, -((float)(2 * (d >> 1)) * (1.f / 32.f)));
  int h = t >> 5;
#pragma unroll
  for (int r = 0; r < 8; ++r) {
    int gr = row0 + r;
    int b = gr >> 10, i = gr & 1023;
    float ang = (float)i * inv;
    float sn, cs;
    sincosf(ang, &sn, &cs);
    float qp = __shfl_xor(qa[r], 1, 64);
    float kp = __shfl_xor(ka[r], 1, 64);
    float qo = (d & 1) ? (qp * sn + qa[r] * cs) : (qa[r] * cs - qp * sn);
    float ko = (d & 1) ? (kp * sn + ka[r] * cs) : (ka[r] * cs - kp * sn);
    int idx = ((b * 8 + h) * 1024 + i) * 32 + d;
    qw[idx] = qo;
    kwb[idx] = f2bf(ko);
    vwb[idx] = f2bf(va[r]);
  }
}

// ---------------- kernel B: fused attention, barrier-free waves ----------
__global__ __launch_bounds__(256) void attn_fused(
    const float* __restrict__ edge, const float* __restrict__ qw,
    const u16* __restrict__ kwb, const u16* __restrict__ vwb,
    const float* __restrict__ We, const float* __restrict__ be,
    const float* __restrict__ mask_f, float* __restrict__ rescat) {
  __shared__ __align__(16) u16 Ew[4][16 * ESTR];   // per-wave E tile (bf16)
  __shared__ __align__(16) float Bg[4][8][20];     // per-wave bias staging
  __shared__ __align__(16) float Pg[4][8][20];     // per-wave p values
  __shared__ float Rg[4][8];                       // per-wave rescale r
  __shared__ __align__(16) float MRG[4][1040];     // epilogue merge

  int bid = blockIdx.x;
  int xcd = bid & 7, slot = bid >> 3;
  int b = xcd >> 2;
  int i = (xcd & 3) * 256 + slot;
  int t = threadIdx.x;
  int lane = t & 63;
  int w = __builtin_amdgcn_readfirstlane(t >> 6);

  int hg = lane >> 4, jl = lane & 15;   // QK/softmax map: heads (hg, hg+4), col jl
  int hD = lane >> 3, sD = lane & 7;    // D-phase map: head hD, octet sD
  int jrl = lane >> 2, c4 = lane & 3;   // staging map: row jrl, quarter c4
  int jh = sD >> 2, do4 = sD & 3;

  // ---- prologue: mask bits, q bf16-packed, We fragments, bias consts ----
  float mi = mask_f[b * 1024 + i];
  u32 mb = 0;
  if (mi != 0.f) {
#pragma unroll
    for (int tt = 0; tt < 16; ++tt) {
      float v = mask_f[b * 1024 + tt * 64 + w * 16 + jl];
      mb |= (v != 0.f ? 1u : 0u) << tt;
    }
  }
  float bes1 = be[hg] * EDGE_SCALE, bes2 = be[hg + 4] * EDGE_SCALE;

  u32 qp1[16], qp2[16];
  {
    const float* q1 = qw + ((size_t)((b * 8 + hg) * 1024 + i)) * 32;
    const float* q2 = qw + ((size_t)((b * 8 + hg + 4) * 1024 + i)) * 32;
#pragma unroll
    for (int e = 0; e < 16; ++e) {
      qp1[e] = (u32)f2bf(q1[2 * e]) | ((u32)f2bf(q1[2 * e + 1]) << 16);
      qp2[e] = (u32)f2bf(q2[2 * e]) | ((u32)f2bf(q2[2 * e + 1]) << 16);
    }
  }

  short8 weA0, weA1;
  {
    int hh = lane & 15, g = lane >> 4;
#pragma unroll
    for (int e = 0; e < 8; ++e) {
      int d0 = g * 8 + e;
      float w0 = (hh < 8) ? We[d0 * 8 + hh] * EDGE_SCALE : 0.f;
      float w1 = (hh < 8) ? We[(d0 + 32) * 8 + hh] * EDGE_SCALE : 0.f;
      weA0[e] = (short)f2bf(w0);
      weA1[e] = (short)f2bf(w1);
    }
  }

  const float* ebase = edge + ((size_t)(b * 1024 + i)) * (1024 * 64);
  const float* gsrc = ebase + (size_t)(w * 16 + jrl) * 64 + c4 * 16;
  u16* ewbase = &Ew[w][0];
  // swizzled LDS addresses (halfs), all loop-invariant:
  int wa0 = jrl * ESTR + (((c4 * 2 + 0) + 3 * jrl) & 7) * 8;  // stage write chunk 0
  int wa1 = jrl * ESTR + (((c4 * 2 + 1) + 3 * jrl) & 7) * 8;  // stage write chunk 1
  int ra0 = jl * ESTR + (((hg + 0) + 3 * jl) & 7) * 8;        // MFMA B-frag d 0..31
  int ra1 = jl * ESTR + (((hg + 4) + 3 * jl) & 7) * 8;        // MFMA B-frag d 32..63

  // ---- stage tile 0 (wave-local; no barrier needed ever) -----------------
  {
    f32x4 a0 = __builtin_nontemporal_load((const f32x4*)(gsrc + 0));
    f32x4 a1 = __builtin_nontemporal_load((const f32x4*)(gsrc + 4));
    f32x4 a2 = __builtin_nontemporal_load((const f32x4*)(gsrc + 8));
    f32x4 a3 = __builtin_nontemporal_load((const f32x4*)(gsrc + 12));
    u32x4 w0, w1;
    w0[0] = cvtpk(a0.x, a0.y); w0[1] = cvtpk(a0.z, a0.w);
    w0[2] = cvtpk(a1.x, a1.y); w0[3] = cvtpk(a1.z, a1.w);
    w1[0] = cvtpk(a2.x, a2.y); w1[1] = cvtpk(a2.z, a2.w);
    w1[2] = cvtpk(a3.x, a3.y); w1[3] = cvtpk(a3.z, a3.w);
    *(u32x4*)(ewbase + wa0) = w0;
    *(u32x4*)(ewbase + wa1) = w1;
  }

  float m1 = NEG_MAX, m2 = NEG_MAX, s1 = 0.f, s2 = 0.f;
  f32x4 av0 = {0.f, 0.f, 0.f, 0.f}, av1 = {0.f, 0.f, 0.f, 0.f};
  f32x4 ae0 = {0.f, 0.f, 0.f, 0.f}, ae1 = {0.f, 0.f, 0.f, 0.f};

  for (int tt = 0; tt < 16; ++tt) {
    int j0 = tt * 64;
    // ---- A: prefetch next tile into regs (nontemporal) -------------------
    bool pf = tt < 15;
    f32x4 st0, st1, st2, st3;
    if (pf) {
      const float* g = gsrc + (size_t)(j0 + 64) * 64;
      st0 = __builtin_nontemporal_load((const f32x4*)(g + 0));
      st1 = __builtin_nontemporal_load((const f32x4*)(g + 4));
      st2 = __builtin_nontemporal_load((const f32x4*)(g + 8));
      st3 = __builtin_nontemporal_load((const f32x4*)(g + 12));
    }
    // ---- K loads (L2), independent of LDS --------------------------------
    int jg = j0 + w * 16 + jl;
    const u16* kr1 = kwb + ((size_t)((b * 8 + hg) * 1024 + jg)) * 32;
    const u16* kr2 = kwb + ((size_t)((b * 8 + hg + 4) * 1024 + jg)) * 32;
    u32x4 k1[4], k2[4];
#pragma unroll
    for (int g = 0; g < 4; ++g) {
      k1[g] = *(const u32x4*)(kr1 + g * 8);
      k2[g] = *(const u32x4*)(kr2 + g * 8);
    }
    // ---- B: edge bias via MFMA (wave's own 16-j chunk) --------------------
    {
      short8 bf0 = *(const short8*)(ewbase + ra0);
      short8 bf1 = *(const short8*)(ewbase + ra1);
      f32x4 bacc = {0.f, 0.f, 0.f, 0.f};
      bacc = __builtin_amdgcn_mfma_f32_16x16x32_bf16(weA0, bf0, bacc, 0, 0, 0);
      bacc = __builtin_amdgcn_mfma_f32_16x16x32_bf16(weA1, bf1, bacc, 0, 0, 0);
      if (lane < 32) {
        Bg[w][hg * 4 + 0][jl] = bacc[0];
        Bg[w][hg * 4 + 1][jl] = bacc[1];
        Bg[w][hg * 4 + 2][jl] = bacc[2];
        Bg[w][hg * 4 + 3][jl] = bacc[3];
      }
    }
    // ---- QK dot (bf16 packed extracts) ------------------------------------
    float qk1 = 0.f, qk2 = 0.f;
#pragma unroll
    for (int g = 0; g < 4; ++g)
#pragma unroll
      for (int e = 0; e < 4; ++e) {
        u32 ka = k1[g][e], qa = qp1[g * 4 + e];
        qk1 = fmaf(asf(ka << 16), asf(qa << 16), qk1);
        qk1 = fmaf(asf(ka & 0xffff0000u), asf(qa & 0xffff0000u), qk1);
        u32 kb = k2[g][e], qb = qp2[g * 4 + e];
        qk2 = fmaf(asf(kb << 16), asf(qb << 16), qk2);
        qk2 = fmaf(asf(kb & 0xffff0000u), asf(qb & 0xffff0000u), qk2);
      }
    // ---- S: online softmax over the wave's 16 j (16-lane groups) ---------
    {
      float bias1 = Bg[w][hg][jl], bias2 = Bg[w][hg + 4][jl];
      bool pm = (mb >> tt) & 1u;
      float l1 = pm ? (NODE_SCALE * qk1 + bias1 + bes1) : NEG_MAX;
      float l2 = pm ? (NODE_SCALE * qk2 + bias2 + bes2) : NEG_MAX;
      float mx1 = l1, mx2 = l2;
#pragma unroll
      for (int off = 1; off < 16; off <<= 1) {
        mx1 = fmaxf(mx1, __shfl_xor(mx1, off, 64));
        mx2 = fmaxf(mx2, __shfl_xor(mx2, off, 64));
      }
      float mn1 = fmaxf(m1, mx1), mn2 = fmaxf(m2, mx2);
      float p1 = __expf(l1 - mn1), p2 = __expf(l2 - mn2);
      float ps1 = p1, ps2 = p2;
#pragma unroll
      for (int off = 1; off < 16; off <<= 1) {
        ps1 += __shfl_xor(ps1, off, 64);
        ps2 += __shfl_xor(ps2, off, 64);
      }
      float r1 = __expf(m1 - mn1), r2 = __expf(m2 - mn2);
      s1 = s1 * r1 + ps1; m1 = mn1;
      s2 = s2 * r2 + ps2; m2 = mn2;
      Pg[w][hg][jl] = p1;
      Pg[w][hg + 4][jl] = p2;
      if (jl == 0) { Rg[w][hg] = r1; Rg[w][hg + 4] = r2; }
    }
    // ---- D: accumulate PV and PE (wave-local LDS reads, in-order pipe) ---
    {
      float r = Rg[w][hD];
      f32x4 pr0 = *(const f32x4*)&Pg[w][hD][0];
      f32x4 pr1 = *(const f32x4*)&Pg[w][hD][4];
      f32x4 pr2 = *(const f32x4*)&Pg[w][hD][8];
      f32x4 pr3 = *(const f32x4*)&Pg[w][hD][12];
      // D1: acc_v over 8 j (half-chunk jh), V dims do4*8..+8
      {
        const u16* vb = vwb + ((size_t)((b * 8 + hD) * 1024 + j0 + w * 16 + jh * 8)) * 32 + do4 * 8;
        f32x4 prA = jh ? pr2 : pr0, prB = jh ? pr3 : pr1;
        f32x4 sv0 = {0.f, 0.f, 0.f, 0.f}, sv1 = {0.f, 0.f, 0.f, 0.f};
#pragma unroll
        for (int x = 0; x < 8; ++x) {
          float p = (x < 4) ? prA[x] : prB[x - 4];
          u32x4 vv = *(const u32x4*)(vb + (size_t)x * 32);
          f32x4 e0 = {asf(vv[0] << 16), asf(vv[0] & 0xffff0000u),
                      asf(vv[1] << 16), asf(vv[1] & 0xffff0000u)};
          f32x4 e1 = {asf(vv[2] << 16), asf(vv[2] & 0xffff0000u),
                      asf(vv[3] << 16), asf(vv[3] & 0xffff0000u)};
          sv0 += e0 * p;
          sv1 += e1 * p;
        }
        av0 = av0 * r + sv0;
        av1 = av1 * r + sv1;
      }
      // D2: acc_e over all 16 j, E dims sD*8..+8 (swizzled chunks)
      {
        f32x4 se0 = {0.f, 0.f, 0.f, 0.f}, se1 = {0.f, 0.f, 0.f, 0.f};
#pragma unroll
        for (int x = 0; x < 16; ++x) {
          float p = (x < 4) ? pr0[x] : (x < 8) ? pr1[x - 4]
                  : (x < 12) ? pr2[x - 8] : pr3[x - 12];
          const u16* ep = ewbase + x * ESTR + ((sD + 3 * x) & 7) * 8;
          u32x4 ee = *(const u32x4*)ep;
          f32x4 e0 = {asf(ee[0] << 16), asf(ee[0] & 0xffff0000u),
                      asf(ee[1] << 16), asf(ee[1] & 0xffff0000u)};
          f32x4 e1 = {asf(ee[2] << 16), asf(ee[2] & 0xffff0000u),
                      asf(ee[3] << 16), asf(ee[3] & 0xffff0000u)};
          se0 += e0 * p;
          se1 += e1 * p;
        }
        ae0 = ae0 * r + se0;
        ae1 = ae1 * r + se1;
      }
    }
    // ---- E: stage next tile (after all reads of current; same-wave order)
    if (pf) {
      u32x4 w0, w1;
      w0[0] = cvtpk(st0.x, st0.y); w0[1] = cvtpk(st0.z, st0.w);
      w0[2] = cvtpk(st1.x, st1.y); w0[3] = cvtpk(st1.z, st1.w);
      w1[0] = cvtpk(st2.x, st2.y); w1[1] = cvtpk(st2.z, st2.w);
      w1[2] = cvtpk(st3.x, st3.y); w1[3] = cvtpk(st3.z, st3.w);
      *(u32x4*)(ewbase + wa0) = w0;
      *(u32x4*)(ewbase + wa1) = w1;
    }
  }

  // ---- epilogue: flash-merge the 4 wave partials --------------------------
  if (jl == 0) {
    MRG[w][hg] = m1; MRG[w][hg + 4] = m2;
    MRG[w][8 + hg] = s1; MRG[w][8 + hg + 4] = s2;
  }
  *(f32x4*)&MRG[w][16 + jh * 256 + hD * 32 + do4 * 8] = av0;
  *(f32x4*)&MRG[w][16 + jh * 256 + hD * 32 + do4 * 8 + 4] = av1;
  *(f32x4*)&MRG[w][528 + hD * 64 + sD * 8] = ae0;
  *(f32x4*)&MRG[w][528 + hD * 64 + sD * 8 + 4] = ae1;
  __syncthreads();
  {
    int h = t >> 5, d = t & 31;
    float mx = fmaxf(fmaxf(MRG[0][h], MRG[1][h]), fmaxf(MRG[2][h], MRG[3][h]));
    float ew[4];
    float ssum = 0.f, vsum = 0.f;
#pragma unroll
    for (int ww = 0; ww < 4; ++ww) {
      ew[ww] = __expf(MRG[ww][h] - mx);
      ssum += MRG[ww][8 + h] * ew[ww];
      vsum += (MRG[ww][16 + h * 32 + d] + MRG[ww][16 + 256 + h * 32 + d]) * ew[ww];
    }
    float inv = 1.f / ssum;
    size_t obase = ((size_t)(b * 1024 + i)) * 768;
    rescat[obase + h * 32 + d] = vsum * inv;
    float e0 = 0.f, e1 = 0.f;
#pragma unroll
    for (int ww = 0; ww < 4; ++ww) {
      e0 += MRG[ww][528 + h * 64 + d] * ew[ww];
      e1 += MRG[ww][528 + h * 64 + 32 + d] * ew[ww];
    }
    rescat[obase + 256 + h * 64 + d] = e0 * inv;
    rescat[obase + 256 + h * 64 + 32 + d] = e1 * inv;
  }
}

// ---------------- kernel C: output projection ----------------------------
__global__ __launch_bounds__(256) void out_proj(
    const float* __restrict__ rescat, const float* __restrict__ Wo,
    const float* __restrict__ bo, float* __restrict__ out) {
  __shared__ __align__(16) float xs[8 * 768];
  int t = threadIdx.x;
  int row0 = blockIdx.x * 8;
#pragma unroll
  for (int p = 0; p < 6; ++p) {
    int f = p * 256 + t;
    *(f32x4*)(&xs[f * 4]) = *(const f32x4*)(rescat + (size_t)row0 * 768 + f * 4);
  }
  __syncthreads();
  float acc[8];
#pragma unroll
  for (int r = 0; r < 8; ++r) acc[r] = 0.f;
  for (int c = 0; c < 768; ++c) {
    float w = Wo[c * 256 + t];
#pragma unroll
    for (int r = 0; r < 8; ++r) acc[r] += xs[r * 768 + c] * w;
  }
  float bias = bo[t];
#pragma unroll
  for (int r = 0; r < 8; ++r)
    out[(size_t)(row0 + r) * 256 + t] = acc[r] + bias;
}

// ---------------- launch ---------------------------------------------------
extern "C" void kernel_launch(void* const* d_in, const int* in_sizes, int n_in,
                              void* d_out, int out_size, void* d_ws, size_t ws_size,
                              hipStream_t stream) {
  const float* node = (const float*)d_in[0];
  const float* edge = (const float*)d_in[1];
  const unsigned char* mask = (const unsigned char*)d_in[2];
  const float* Wq = (const float*)d_in[3];
  const float* Wk = (const float*)d_in[4];
  const float* Wv = (const float*)d_in[5];
  const float* We = (const float*)d_in[6];
  const float* be = (const float*)d_in[7];
  const float* Wo = (const float*)d_in[8];
  const float* bo = (const float*)d_in[9];

  float* ws = (float*)d_ws;
  float* qw = ws;                              // 524288 f32
  u16* kwb = (u16*)(ws + 524288);              // 524288 bf16
  u16* vwb = kwb + 524288;                     // 524288 bf16
  float* rescat = ws + 1048576;                // 1572864 f32
  float* mask_f = ws + 2621440;                // 2048 f32

  hipLaunchKernelGGL(mask_norm, dim3(1), dim3(256), 0, stream, mask, mask_f);
  hipLaunchKernelGGL(qkv_rope, dim3(256), dim3(256), 0, stream,
                     node, Wq, Wk, Wv, qw, kwb, vwb);
  hipLaunchKernelGGL(attn_fused, dim3(2048), dim3(256), 0, stream,
                     edge, qw, kwb, vwb, We, be, mask_f, rescat);
  hipLaunchKernelGGL(out_proj, dim3(256), dim3(256), 0, stream,
                     rescat, Wo, bo, (float*)d_out);
}

// Round 8
// 395.461 us; speedup vs baseline: 7.6009x; 1.0252x over previous
//
#include <hip/hip_runtime.h>
#include <hip/hip_bf16.h>

typedef float f32x4 __attribute__((ext_vector_type(4)));
typedef short short8 __attribute__((ext_vector_type(8)));
typedef unsigned short u16;
typedef unsigned int u32;
typedef unsigned int u32x4 __attribute__((ext_vector_type(4)));
typedef unsigned short u16x8 __attribute__((ext_vector_type(8)));

#define NEG_MAX (-3.4028234663852886e38f)
#define NODE_SCALE 0.125f
#define EDGE_SCALE 0.70710678118654752f
#define TSTR 68  // f32 per E-tile row
#define QSTR 36  // f32 per q row (bank-spread)

__device__ __forceinline__ float bf2f(u16 u) {
  unsigned int w = ((unsigned int)u) << 16;
  return __builtin_bit_cast(float, w);
}
__device__ __forceinline__ u16 f2bf(float f) {
  unsigned int x = __builtin_bit_cast(unsigned int, f);
  x = x + 0x7FFFu + ((x >> 16) & 1u);
  return (u16)(x >> 16);
}
__device__ __forceinline__ float asf(u32 x) { return __builtin_bit_cast(float, x); }
__device__ __forceinline__ u32 cvtpk(float lo, float hi) {
  u32 r;
  asm("v_cvt_pk_bf16_f32 %0, %1, %2" : "=v"(r) : "v"(lo), "v"(hi));
  return r;
}

// ---------------- kernel M: normalize mask to float 0/1 (dtype-robust) ----
__global__ void mask_norm(const unsigned char* __restrict__ mraw,
                          float* __restrict__ mask_f) {
  __shared__ int flags;
  int t = threadIdx.x;
  if (t == 0) flags = 0;
  __syncthreads();
  const unsigned int* mu = (const unsigned int*)mraw;
  int f = 0;
  for (int e = t; e < 512; e += 256) { if (mu[e] > 1u) f |= 1; }
  for (int e = t; e < 2048; e += 256) { if (mraw[e] > 1) f |= 2; }
  if (f) atomicOr(&flags, f);
  __syncthreads();
  int fl = flags;
  for (int e = t; e < 2048; e += 256) {
    float v;
    if (!(fl & 1))      v = (mu[e] != 0u) ? 1.f : 0.f;
    else if (!(fl & 2)) v = (mraw[e] != 0) ? 1.f : 0.f;
    else                v = (((const float*)mraw)[e] != 0.f) ? 1.f : 0.f;
    mask_f[e] = v;
  }
}

// ---------------- kernel A: qkv projection + rotary ----------------------
__global__ __launch_bounds__(256) void qkv_rope(
    const float* __restrict__ node, const float* __restrict__ Wq,
    const float* __restrict__ Wk, const float* __restrict__ Wv,
    float* __restrict__ qw, u16* __restrict__ kwb, u16* __restrict__ vwb) {
  __shared__ __align__(16) float xs[8 * 256];
  int t = threadIdx.x;
  int row0 = blockIdx.x * 8;
#pragma unroll
  for (int p = 0; p < 2; ++p) {
    int f = p * 256 + t;
    *(f32x4*)(&xs[f * 4]) = *(const f32x4*)(node + (size_t)row0 * 256 + f * 4);
  }
  __syncthreads();
  float qa[8], ka[8], va[8];
#pragma unroll
  for (int r = 0; r < 8; ++r) { qa[r] = 0.f; ka[r] = 0.f; va[r] = 0.f; }
  for (int c = 0; c < 256; ++c) {
    float wq = Wq[c * 256 + t];
    float wk = Wk[c * 256 + t];
    float wv = Wv[c * 256 + t];
#pragma unroll
    for (int r = 0; r < 8; ++r) {
      float x = xs[r * 256 + c];
      qa[r] += x * wq; ka[r] += x * wk; va[r] += x * wv;
    }
  }
  int d = t & 31;
  float inv = powf(10000.f, -((float)(2 * (d >> 1)) * (1.f / 32.f)));
  int h = t >> 5;
#pragma unroll
  for (int r = 0; r < 8; ++r) {
    int gr = row0 + r;
    int b = gr >> 10, i = gr & 1023;
    float ang = (float)i * inv;
    float sn, cs;
    sincosf(ang, &sn, &cs);
    float qp = __shfl_xor(qa[r], 1, 64);
    float kp = __shfl_xor(ka[r], 1, 64);
    float qo = (d & 1) ? (qp * sn + qa[r] * cs) : (qa[r] * cs - qp * sn);
    float ko = (d & 1) ? (kp * sn + ka[r] * cs) : (ka[r] * cs - kp * sn);
    int idx = ((b * 8 + h) * 1024 + i) * 32 + d;
    qw[idx] = qo;
    kwb[idx] = f2bf(ko);
    vwb[idx] = f2bf(va[r]);
  }
}

// ---------------- kernel B: fused attention, barrier-free waves ----------
// Per-wave LDS region (f32 idx): [tile 16*68][Pf 8*20][Bg 8*20][qsw 8*36][Rg 8]
#define WREG 1704
__global__ __launch_bounds__(256) void attn_fused(
    const float* __restrict__ edge, const float* __restrict__ qw,
    const u16* __restrict__ kwb, const u16* __restrict__ vwb,
    const float* __restrict__ We, const float* __restrict__ be,
    const float* __restrict__ mask_f, float* __restrict__ rescat) {
  __shared__ __align__(16) float S[4 * WREG];  // 27.3 KB; epilogue reuses as MRG

  int bid = blockIdx.x;
  int xcd = bid & 7, slot = bid >> 3;
  int b = xcd >> 2;
  int i = (xcd & 3) * 256 + slot;
  int t = threadIdx.x;
  int lane = t & 63;
  int w = __builtin_amdgcn_readfirstlane(t >> 6);

  float* tile = S + w * WREG;
  float* Pf = tile + 1088;
  float* Bg = Pf + 160;
  float* qsw = Bg + 160;
  float* Rg = qsw + 288;

  int hg = lane >> 4, jl = lane & 15;   // QK/softmax map: heads (hg, hg+4)
  int hD = lane >> 3, sD = lane & 7;    // D-phase map: head hD, octet sD
  int jrl = lane >> 2, c4 = lane & 3;   // staging map
  int jh = sD >> 2, do4 = sD & 3;

  // ---- prologue ----------------------------------------------------------
  float mi = mask_f[b * 1024 + i];
  u32 mb = 0;
  if (mi != 0.f) {
#pragma unroll
    for (int tt = 0; tt < 16; ++tt) {
      float v = mask_f[b * 1024 + tt * 64 + w * 16 + jl];
      mb |= (v != 0.f ? 1u : 0u) << tt;
    }
  }
  float bes1 = be[hg] * EDGE_SCALE, bes2 = be[hg + 4] * EDGE_SCALE;

  // q rows for ALL 8 heads, wave-local copy (head = lane>>3, dims (lane&7)*4..+3)
  {
    int qh = lane >> 3, qd = (lane & 7) * 4;
    f32x4 qv = *(const f32x4*)(qw + ((size_t)((b * 8 + qh) * 1024 + i)) * 32 + qd);
    *(f32x4*)(qsw + qh * QSTR + qd) = qv;
  }

  short8 weA0, weA1;
  {
    int hh = lane & 15, g = lane >> 4;
#pragma unroll
    for (int e = 0; e < 8; ++e) {
      int d0 = g * 8 + e;
      float w0 = (hh < 8) ? We[d0 * 8 + hh] * EDGE_SCALE : 0.f;
      float w1 = (hh < 8) ? We[(d0 + 32) * 8 + hh] * EDGE_SCALE : 0.f;
      weA0[e] = (short)f2bf(w0);
      weA1[e] = (short)f2bf(w1);
    }
  }

  const float* ebase = edge + ((size_t)(b * 1024 + i)) * (1024 * 64);
  const float* gsrc = ebase + (size_t)(w * 16 + jrl) * 64 + c4 * 16;
  float* wdst = tile + jrl * TSTR + c4 * 16;

  // stage tile 0 (wave-local, in-order DS pipe -> no barrier in loop)
  {
    f32x4 a0 = __builtin_nontemporal_load((const f32x4*)(gsrc + 0));
    f32x4 a1 = __builtin_nontemporal_load((const f32x4*)(gsrc + 4));
    f32x4 a2 = __builtin_nontemporal_load((const f32x4*)(gsrc + 8));
    f32x4 a3 = __builtin_nontemporal_load((const f32x4*)(gsrc + 12));
    *(f32x4*)(wdst + 0) = a0;
    *(f32x4*)(wdst + 4) = a1;
    *(f32x4*)(wdst + 8) = a2;
    *(f32x4*)(wdst + 12) = a3;
  }

  float m1 = NEG_MAX, m2 = NEG_MAX, s1 = 0.f, s2 = 0.f;
  f32x4 av0 = {0.f, 0.f, 0.f, 0.f}, av1 = {0.f, 0.f, 0.f, 0.f};
  f32x4 ae0 = {0.f, 0.f, 0.f, 0.f}, ae1 = {0.f, 0.f, 0.f, 0.f};

  for (int tt = 0; tt < 16; ++tt) {
    int j0 = tt * 64;
    bool pf = tt < 15;
    f32x4 st0, st1, st2, st3;
    if (pf) {
      const float* g = gsrc + (size_t)(j0 + 64) * 64;
      st0 = __builtin_nontemporal_load((const f32x4*)(g + 0));
      st1 = __builtin_nontemporal_load((const f32x4*)(g + 4));
      st2 = __builtin_nontemporal_load((const f32x4*)(g + 8));
      st3 = __builtin_nontemporal_load((const f32x4*)(g + 12));
    }
    // ---- K loads (L2) -----------------------------------------------------
    int jg = j0 + w * 16 + jl;
    const u16* kr1 = kwb + ((size_t)((b * 8 + hg) * 1024 + jg)) * 32;
    const u16* kr2 = kwb + ((size_t)((b * 8 + hg + 4) * 1024 + jg)) * 32;
    u32x4 k1[4], k2[4];
#pragma unroll
    for (int g = 0; g < 4; ++g) {
      k1[g] = *(const u32x4*)(kr1 + g * 8);
      k2[g] = *(const u32x4*)(kr2 + g * 8);
    }
    // ---- bias via MFMA (f32 tile -> bf16 frags) ---------------------------
    {
      const float* rp = tile + jl * TSTR + hg * 8;
      f32x4 ea0 = *(const f32x4*)(rp + 0);
      f32x4 ea1 = *(const f32x4*)(rp + 4);
      f32x4 eb0 = *(const f32x4*)(rp + 32);
      f32x4 eb1 = *(const f32x4*)(rp + 36);
      u32x4 p0, p1;
      p0[0] = cvtpk(ea0.x, ea0.y); p0[1] = cvtpk(ea0.z, ea0.w);
      p0[2] = cvtpk(ea1.x, ea1.y); p0[3] = cvtpk(ea1.z, ea1.w);
      p1[0] = cvtpk(eb0.x, eb0.y); p1[1] = cvtpk(eb0.z, eb0.w);
      p1[2] = cvtpk(eb1.x, eb1.y); p1[3] = cvtpk(eb1.z, eb1.w);
      short8 bf0 = __builtin_bit_cast(short8, p0);
      short8 bf1 = __builtin_bit_cast(short8, p1);
      f32x4 bacc = {0.f, 0.f, 0.f, 0.f};
      bacc = __builtin_amdgcn_mfma_f32_16x16x32_bf16(weA0, bf0, bacc, 0, 0, 0);
      bacc = __builtin_amdgcn_mfma_f32_16x16x32_bf16(weA1, bf1, bacc, 0, 0, 0);
      if (lane < 32) {
        float* bg = Bg + hg * 80 + jl;  // rows (hg*4 .. hg*4+3), stride 20
        bg[0] = bacc[0];
        bg[20] = bacc[1];
        bg[40] = bacc[2];
        bg[60] = bacc[3];
      }
    }
    // ---- QK dot (q f32 from LDS, per-lane-group head hg / hg+4) -----------
    float qk1 = 0.f, qk2 = 0.f;
    {
      const float* q1p = qsw + hg * QSTR;
      const float* q2p = qsw + (hg + 4) * QSTR;
#pragma unroll
      for (int g = 0; g < 4; ++g) {
        f32x4 q1a = *(const f32x4*)(q1p + g * 8);
        f32x4 q1b = *(const f32x4*)(q1p + g * 8 + 4);
        f32x4 q2a = *(const f32x4*)(q2p + g * 8);
        f32x4 q2b = *(const f32x4*)(q2p + g * 8 + 4);
        u32 ka0 = k1[g][0], ka1 = k1[g][1], ka2 = k1[g][2], ka3 = k1[g][3];
        u32 kb0 = k2[g][0], kb1 = k2[g][1], kb2 = k2[g][2], kb3 = k2[g][3];
        qk1 = fmaf(asf(ka0 << 16), q1a.x, qk1);
        qk1 = fmaf(asf(ka0 & 0xffff0000u), q1a.y, qk1);
        qk1 = fmaf(asf(ka1 << 16), q1a.z, qk1);
        qk1 = fmaf(asf(ka1 & 0xffff0000u), q1a.w, qk1);
        qk1 = fmaf(asf(ka2 << 16), q1b.x, qk1);
        qk1 = fmaf(asf(ka2 & 0xffff0000u), q1b.y, qk1);
        qk1 = fmaf(asf(ka3 << 16), q1b.z, qk1);
        qk1 = fmaf(asf(ka3 & 0xffff0000u), q1b.w, qk1);
        qk2 = fmaf(asf(kb0 << 16), q2a.x, qk2);
        qk2 = fmaf(asf(kb0 & 0xffff0000u), q2a.y, qk2);
        qk2 = fmaf(asf(kb1 << 16), q2a.z, qk2);
        qk2 = fmaf(asf(kb1 & 0xffff0000u), q2a.w, qk2);
        qk2 = fmaf(asf(kb2 << 16), q2b.x, qk2);
        qk2 = fmaf(asf(kb2 & 0xffff0000u), q2b.y, qk2);
        qk2 = fmaf(asf(kb3 << 16), q2b.z, qk2);
        qk2 = fmaf(asf(kb3 & 0xffff0000u), q2b.w, qk2);
      }
    }
    // ---- online softmax over the wave's 16 j ------------------------------
    {
      float bias1 = Bg[hg * 20 + jl], bias2 = Bg[(hg + 4) * 20 + jl];
      bool pm = (mb >> tt) & 1u;
      float l1 = pm ? (NODE_SCALE * qk1 + bias1 + bes1) : NEG_MAX;
      float l2 = pm ? (NODE_SCALE * qk2 + bias2 + bes2) : NEG_MAX;
      float mx1 = l1, mx2 = l2;
#pragma unroll
      for (int off = 1; off < 16; off <<= 1) {
        mx1 = fmaxf(mx1, __shfl_xor(mx1, off, 64));
        mx2 = fmaxf(mx2, __shfl_xor(mx2, off, 64));
      }
      float mn1 = fmaxf(m1, mx1), mn2 = fmaxf(m2, mx2);
      float p1 = __expf(l1 - mn1), p2 = __expf(l2 - mn2);
      float ps1 = p1, ps2 = p2;
#pragma unroll
      for (int off = 1; off < 16; off <<= 1) {
        ps1 += __shfl_xor(ps1, off, 64);
        ps2 += __shfl_xor(ps2, off, 64);
      }
      float r1 = __expf(m1 - mn1), r2 = __expf(m2 - mn2);
      s1 = s1 * r1 + ps1; m1 = mn1;
      s2 = s2 * r2 + ps2; m2 = mn2;
      Pf[hg * 20 + jl] = p1;
      Pf[(hg + 4) * 20 + jl] = p2;
      if (jl == 0) { Rg[hg] = r1; Rg[hg + 4] = r2; }
    }
    // ---- D: PV + PE (wave-local, in-order) --------------------------------
    {
      float r = Rg[hD];
      const float* prow = Pf + hD * 20;
      f32x4 pr0 = *(const f32x4*)(prow + 0);
      f32x4 pr1 = *(const f32x4*)(prow + 4);
      f32x4 pr2 = *(const f32x4*)(prow + 8);
      f32x4 pr3 = *(const f32x4*)(prow + 12);
      // D1: acc_v over 8 j (half jh), V dims do4*8..+8
      {
        const u16* vb = vwb + ((size_t)((b * 8 + hD) * 1024 + j0 + w * 16 + jh * 8)) * 32 + do4 * 8;
        f32x4 prA = jh ? pr2 : pr0, prB = jh ? pr3 : pr1;
        f32x4 sv0 = {0.f, 0.f, 0.f, 0.f}, sv1 = {0.f, 0.f, 0.f, 0.f};
#pragma unroll
        for (int x = 0; x < 8; ++x) {
          float p = (x < 4) ? prA[x] : prB[x - 4];
          u32x4 vv = *(const u32x4*)(vb + (size_t)x * 32);
          f32x4 e0 = {asf(vv[0] << 16), asf(vv[0] & 0xffff0000u),
                      asf(vv[1] << 16), asf(vv[1] & 0xffff0000u)};
          f32x4 e1 = {asf(vv[2] << 16), asf(vv[2] & 0xffff0000u),
                      asf(vv[3] << 16), asf(vv[3] & 0xffff0000u)};
          sv0 += e0 * p;
          sv1 += e1 * p;
        }
        av0 = av0 * r + sv0;
        av1 = av1 * r + sv1;
      }
      // D2: acc_e over 16 j, E dims sD*8..+8 (f32 tile, broadcast reads)
      {
        const float* eB = tile + sD * 8;
        f32x4 se0 = {0.f, 0.f, 0.f, 0.f}, se1 = {0.f, 0.f, 0.f, 0.f};
#pragma unroll
        for (int x = 0; x < 16; ++x) {
          float p = (x < 4) ? pr0[x] : (x < 8) ? pr1[x - 4]
                  : (x < 12) ? pr2[x - 8] : pr3[x - 12];
          f32x4 e0 = *(const f32x4*)(eB + x * TSTR);
          f32x4 e1 = *(const f32x4*)(eB + x * TSTR + 4);
          se0 += e0 * p;
          se1 += e1 * p;
        }
        ae0 = ae0 * r + se0;
        ae1 = ae1 * r + se1;
      }
    }
    // ---- stage next tile (after all reads; same-wave DS order) ------------
    if (pf) {
      *(f32x4*)(wdst + 0) = st0;
      *(f32x4*)(wdst + 4) = st1;
      *(f32x4*)(wdst + 8) = st2;
      *(f32x4*)(wdst + 12) = st3;
    }
  }

  // ---- epilogue: flash-merge 4 wave partials (S reused as MRG) ------------
  __syncthreads();
  float* mrg = S + w * 1040;
  if (jl == 0) {
    mrg[hg] = m1; mrg[hg + 4] = m2;
    mrg[8 + hg] = s1; mrg[8 + hg + 4] = s2;
  }
  *(f32x4*)(mrg + 16 + jh * 256 + hD * 32 + do4 * 8) = av0;
  *(f32x4*)(mrg + 16 + jh * 256 + hD * 32 + do4 * 8 + 4) = av1;
  *(f32x4*)(mrg + 528 + hD * 64 + sD * 8) = ae0;
  *(f32x4*)(mrg + 528 + hD * 64 + sD * 8 + 4) = ae1;
  __syncthreads();
  {
    int h = t >> 5, d = t & 31;
    float mx = fmaxf(fmaxf(S[h], S[1040 + h]), fmaxf(S[2080 + h], S[3120 + h]));
    float ew[4];
    float ssum = 0.f, vsum = 0.f;
#pragma unroll
    for (int ww = 0; ww < 4; ++ww) {
      const float* mw = S + ww * 1040;
      ew[ww] = __expf(mw[h] - mx);
      ssum += mw[8 + h] * ew[ww];
      vsum += (mw[16 + h * 32 + d] + mw[16 + 256 + h * 32 + d]) * ew[ww];
    }
    float inv = 1.f / ssum;
    size_t obase = ((size_t)(b * 1024 + i)) * 768;
    rescat[obase + h * 32 + d] = vsum * inv;
    float e0 = 0.f, e1 = 0.f;
#pragma unroll
    for (int ww = 0; ww < 4; ++ww) {
      const float* mw = S + ww * 1040;
      e0 += mw[528 + h * 64 + d] * ew[ww];
      e1 += mw[528 + h * 64 + 32 + d] * ew[ww];
    }
    rescat[obase + 256 + h * 64 + d] = e0 * inv;
    rescat[obase + 256 + h * 64 + 32 + d] = e1 * inv;
  }
}

// ---------------- kernel C: output projection ----------------------------
__global__ __launch_bounds__(256) void out_proj(
    const float* __restrict__ rescat, const float* __restrict__ Wo,
    const float* __restrict__ bo, float* __restrict__ out) {
  __shared__ __align__(16) float xs[8 * 768];
  int t = threadIdx.x;
  int row0 = blockIdx.x * 8;
#pragma unroll
  for (int p = 0; p < 6; ++p) {
    int f = p * 256 + t;
    *(f32x4*)(&xs[f * 4]) = *(const f32x4*)(rescat + (size_t)row0 * 768 + f * 4);
  }
  __syncthreads();
  float acc[8];
#pragma unroll
  for (int r = 0; r < 8; ++r) acc[r] = 0.f;
  for (int c = 0; c < 768; ++c) {
    float w = Wo[c * 256 + t];
#pragma unroll
    for (int r = 0; r < 8; ++r) acc[r] += xs[r * 768 + c] * w;
  }
  float bias = bo[t];
#pragma unroll
  for (int r = 0; r < 8; ++r)
    out[(size_t)(row0 + r) * 256 + t] = acc[r] + bias;
}

// ---------------- launch ---------------------------------------------------
extern "C" void kernel_launch(void* const* d_in, const int* in_sizes, int n_in,
                              void* d_out, int out_size, void* d_ws, size_t ws_size,
                              hipStream_t stream) {
  const float* node = (const float*)d_in[0];
  const float* edge = (const float*)d_in[1];
  const unsigned char* mask = (const unsigned char*)d_in[2];
  const float* Wq = (const float*)d_in[3];
  const float* Wk = (const float*)d_in[4];
  const float* Wv = (const float*)d_in[5];
  const float* We = (const float*)d_in[6];
  const float* be = (const float*)d_in[7];
  const float* Wo = (const float*)d_in[8];
  const float* bo = (const float*)d_in[9];

  float* ws = (float*)d_ws;
  float* qw = ws;                              // 524288 f32
  u16* kwb = (u16*)(ws + 524288);              // 524288 bf16
  u16* vwb = kwb + 524288;                     // 524288 bf16
  float* rescat = ws + 1048576;                // 1572864 f32
  float* mask_f = ws + 2621440;                // 2048 f32

  hipLaunchKernelGGL(mask_norm, dim3(1), dim3(256), 0, stream, mask, mask_f);
  hipLaunchKernelGGL(qkv_rope, dim3(256), dim3(256), 0, stream,
                     node, Wq, Wk, Wv, qw, kwb, vwb);
  hipLaunchKernelGGL(attn_fused, dim3(2048), dim3(256), 0, stream,
                     edge, qw, kwb, vwb, We, be, mask_f, rescat);
  hipLaunchKernelGGL(out_proj, dim3(256), dim3(256), 0, stream,
                     rescat, Wo, bo, (float*)d_out);
}

// Round 9
// 393.760 us; speedup vs baseline: 7.6337x; 1.0043x over previous
//
#include <hip/hip_runtime.h>
#include <hip/hip_bf16.h>

typedef float f32x4 __attribute__((ext_vector_type(4)));
typedef short short8 __attribute__((ext_vector_type(8)));
typedef unsigned short u16;
typedef unsigned int u32;
typedef unsigned int u32x4 __attribute__((ext_vector_type(4)));

#define NEG_MAX (-3.4028234663852886e38f)
#define NODE_SCALE 0.125f
#define EDGE_SCALE 0.70710678118654752f
#define TSTR 68   // f32 per E-tile row

__device__ __forceinline__ u16 f2bf(float f) {
  unsigned int x = __builtin_bit_cast(unsigned int, f);
  x = x + 0x7FFFu + ((x >> 16) & 1u);
  return (u16)(x >> 16);
}
__device__ __forceinline__ float asf(u32 x) { return __builtin_bit_cast(float, x); }
__device__ __forceinline__ u32 cvtpk(float lo, float hi) {
  u32 r;
  asm("v_cvt_pk_bf16_f32 %0, %1, %2" : "=v"(r) : "v"(lo), "v"(hi));
  return r;
}

// ---------------- kernel M: normalize mask to float 0/1 (dtype-robust) ----
__global__ void mask_norm(const unsigned char* __restrict__ mraw,
                          float* __restrict__ mask_f) {
  __shared__ int flags;
  int t = threadIdx.x;
  if (t == 0) flags = 0;
  __syncthreads();
  const unsigned int* mu = (const unsigned int*)mraw;
  int f = 0;
  for (int e = t; e < 512; e += 256) { if (mu[e] > 1u) f |= 1; }
  for (int e = t; e < 2048; e += 256) { if (mraw[e] > 1) f |= 2; }
  if (f) atomicOr(&flags, f);
  __syncthreads();
  int fl = flags;
  for (int e = t; e < 2048; e += 256) {
    float v;
    if (!(fl & 1))      v = (mu[e] != 0u) ? 1.f : 0.f;
    else if (!(fl & 2)) v = (mraw[e] != 0) ? 1.f : 0.f;
    else                v = (((const float*)mraw)[e] != 0.f) ? 1.f : 0.f;
    mask_f[e] = v;
  }
}

// ---------------- kernel A: qkv projection + rotary ----------------------
__global__ __launch_bounds__(256) void qkv_rope(
    const float* __restrict__ node, const float* __restrict__ Wq,
    const float* __restrict__ Wk, const float* __restrict__ Wv,
    float* __restrict__ qw, u16* __restrict__ kwb, u16* __restrict__ vwb) {
  __shared__ __align__(16) float xs[8 * 256];
  int t = threadIdx.x;
  int row0 = blockIdx.x * 8;
#pragma unroll
  for (int p = 0; p < 2; ++p) {
    int f = p * 256 + t;
    *(f32x4*)(&xs[f * 4]) = *(const f32x4*)(node + (size_t)row0 * 256 + f * 4);
  }
  __syncthreads();
  float qa[8], ka[8], va[8];
#pragma unroll
  for (int r = 0; r < 8; ++r) { qa[r] = 0.f; ka[r] = 0.f; va[r] = 0.f; }
  for (int c = 0; c < 256; ++c) {
    float wq = Wq[c * 256 + t];
    float wk = Wk[c * 256 + t];
    float wv = Wv[c * 256 + t];
#pragma unroll
    for (int r = 0; r < 8; ++r) {
      float x = xs[r * 256 + c];
      qa[r] += x * wq; ka[r] += x * wk; va[r] += x * wv;
    }
  }
  int d = t & 31;
  float inv = powf(10000.f, -((float)(2 * (d >> 1)) * (1.f / 32.f)));
  int h = t >> 5;
#pragma unroll
  for (int r = 0; r < 8; ++r) {
    int gr = row0 + r;
    int b = gr >> 10, i = gr & 1023;
    float ang = (float)i * inv;
    float sn, cs;
    sincosf(ang, &sn, &cs);
    float qp = __shfl_xor(qa[r], 1, 64);
    float kp = __shfl_xor(ka[r], 1, 64);
    float qo = (d & 1) ? (qp * sn + qa[r] * cs) : (qa[r] * cs - qp * sn);
    float ko = (d & 1) ? (kp * sn + ka[r] * cs) : (ka[r] * cs - kp * sn);
    int idx = ((b * 8 + h) * 1024 + i) * 32 + d;
    qw[idx] = qo;
    kwb[idx] = f2bf(ko);
    vwb[idx] = f2bf(va[r]);
  }
}

// ---------------- kernel B: fused attention, barrier-free waves ----------
// Per-wave LDS (f32 idx): [tile 16*68 = 1088][Pf 8*20 = 160][Rg 8][pad]
#define WREG 1280
__global__ __launch_bounds__(256) void attn_fused(
    const float* __restrict__ edge, const float* __restrict__ qw,
    const u16* __restrict__ kwb, const u16* __restrict__ vwb,
    const float* __restrict__ We, const float* __restrict__ be,
    const float* __restrict__ mask_f, float* __restrict__ rescat) {
  __shared__ __align__(16) float S[4 * WREG];  // 20.5 KB; epilogue reuses as MRG

  int bid = blockIdx.x;
  int xcd = bid & 7, slot = bid >> 3;
  int b = xcd >> 2;
  int i = (xcd & 3) * 256 + slot;
  int t = threadIdx.x;
  int lane = t & 63;
  int w = __builtin_amdgcn_readfirstlane(t >> 6);

  float* tile = S + w * WREG;
  float* Pf = tile + 1088;
  float* Rg = tile + 1248;

  int j16 = lane & 15;                 // MFMA C column / j within wave chunk
  int hq = lane >> 4;                  // C row-quad (valid logits hq<2)
  int hD = lane >> 3, sD = lane & 7;   // D1 map: head hD, octet sD
  int jrl = lane >> 2, c4 = lane & 3;  // staging map
  int jh = sD >> 2, do4 = sD & 3;

  // ---- prologue ----------------------------------------------------------
  float mi = mask_f[b * 1024 + i];
  u32 mb = 0;
  if (mi != 0.f) {
#pragma unroll
    for (int tt = 0; tt < 16; ++tt) {
      float v = mask_f[b * 1024 + tt * 64 + w * 16 + j16];
      mb |= (v != 0.f ? 1u : 0u) << tt;
    }
  }
  f32x4 besq = *(const f32x4*)(be + (hq & 1) * 4);
  besq *= EDGE_SCALE;

  // We^T A-fragments (rows h>=8 zero, EDGE_SCALE folded)
  short8 weA0, weA1;
  {
    int hh = lane & 15, g = lane >> 4;
#pragma unroll
    for (int e = 0; e < 8; ++e) {
      int d0 = g * 8 + e;
      float w0 = (hh < 8) ? We[d0 * 8 + hh] * EDGE_SCALE : 0.f;
      float w1 = (hh < 8) ? We[(d0 + 32) * 8 + hh] * EDGE_SCALE : 0.f;
      weA0[e] = (short)f2bf(w0);
      weA1[e] = (short)f2bf(w1);
    }
  }

  // q A-fragments: block-diagonal, 8 frags (step h has only row h nonzero),
  // NODE_SCALE folded. Built once.
  short8 qA[8];
  {
    int hh = (lane & 15) & 7;
    const float* qp = qw + ((size_t)((b * 8 + hh) * 1024 + i)) * 32 + (lane >> 4) * 8;
    f32x4 qv0 = *(const f32x4*)(qp);
    f32x4 qv1 = *(const f32x4*)(qp + 4);
    qv0 *= NODE_SCALE;
    qv1 *= NODE_SCALE;
    u32x4 qpk;
    qpk[0] = cvtpk(qv0.x, qv0.y); qpk[1] = cvtpk(qv0.z, qv0.w);
    qpk[2] = cvtpk(qv1.x, qv1.y); qpk[3] = cvtpk(qv1.z, qv1.w);
    u32x4 zz = {0u, 0u, 0u, 0u};
#pragma unroll
    for (int h = 0; h < 8; ++h)
      qA[h] = __builtin_bit_cast(short8, ((lane & 15) == h) ? qpk : zz);
  }

  const float* ebase = edge + ((size_t)(b * 1024 + i)) * (1024 * 64);
  const float* gsrc = ebase + (size_t)(w * 16 + jrl) * 64 + c4 * 16;
  float* wdst = tile + jrl * TSTR + c4 * 16;

  // stage tile 0 (wave-local; in-order DS pipe -> no barrier in loop)
  {
    f32x4 a0 = __builtin_nontemporal_load((const f32x4*)(gsrc + 0));
    f32x4 a1 = __builtin_nontemporal_load((const f32x4*)(gsrc + 4));
    f32x4 a2 = __builtin_nontemporal_load((const f32x4*)(gsrc + 8));
    f32x4 a3 = __builtin_nontemporal_load((const f32x4*)(gsrc + 12));
    *(f32x4*)(wdst + 0) = a0;
    *(f32x4*)(wdst + 4) = a1;
    *(f32x4*)(wdst + 8) = a2;
    *(f32x4*)(wdst + 12) = a3;
  }

  f32x4 vm = {NEG_MAX, NEG_MAX, NEG_MAX, NEG_MAX};
  f32x4 vs = {0.f, 0.f, 0.f, 0.f};
  f32x4 av0 = {0.f, 0.f, 0.f, 0.f}, av1 = {0.f, 0.f, 0.f, 0.f};
  f32x4 acce0 = {0.f, 0.f, 0.f, 0.f}, acce1 = {0.f, 0.f, 0.f, 0.f};
  f32x4 acce2 = {0.f, 0.f, 0.f, 0.f}, acce3 = {0.f, 0.f, 0.f, 0.f};

  for (int tt = 0; tt < 16; ++tt) {
    int j0 = tt * 64;
    bool pf = tt < 15;
    f32x4 st0, st1, st2, st3;
    if (pf) {
      const float* g = gsrc + (size_t)(j0 + 64) * 64;
      st0 = __builtin_nontemporal_load((const f32x4*)(g + 0));
      st1 = __builtin_nontemporal_load((const f32x4*)(g + 4));
      st2 = __builtin_nontemporal_load((const f32x4*)(g + 8));
      st3 = __builtin_nontemporal_load((const f32x4*)(g + 12));
    }

    // ---- logits: 2 bias MFMAs + 8 block-diagonal QK MFMAs, one C ---------
    f32x4 bacc = {0.f, 0.f, 0.f, 0.f};
    {
      const float* rp = tile + j16 * TSTR + hq * 8;
      f32x4 ea0 = *(const f32x4*)(rp + 0);
      f32x4 ea1 = *(const f32x4*)(rp + 4);
      f32x4 eb0 = *(const f32x4*)(rp + 32);
      f32x4 eb1 = *(const f32x4*)(rp + 36);
      u32x4 p0, p1;
      p0[0] = cvtpk(ea0.x, ea0.y); p0[1] = cvtpk(ea0.z, ea0.w);
      p0[2] = cvtpk(ea1.x, ea1.y); p0[3] = cvtpk(ea1.z, ea1.w);
      p1[0] = cvtpk(eb0.x, eb0.y); p1[1] = cvtpk(eb0.z, eb0.w);
      p1[2] = cvtpk(eb1.x, eb1.y); p1[3] = cvtpk(eb1.z, eb1.w);
      bacc = __builtin_amdgcn_mfma_f32_16x16x32_bf16(
          weA0, __builtin_bit_cast(short8, p0), bacc, 0, 0, 0);
      bacc = __builtin_amdgcn_mfma_f32_16x16x32_bf16(
          weA1, __builtin_bit_cast(short8, p1), bacc, 0, 0, 0);
    }
#pragma unroll
    for (int h = 0; h < 8; ++h) {
      const u16* kp = kwb + ((size_t)((b * 8 + h) * 1024 + j0 + w * 16 + j16)) * 32 + hq * 8;
      short8 kB = *(const short8*)kp;
      bacc = __builtin_amdgcn_mfma_f32_16x16x32_bf16(qA[h], kB, bacc, 0, 0, 0);
    }

    // ---- online softmax (C layout: col j16, rows hq*4..+3) ---------------
    f32x4 p;
    {
      bool pm = (mb >> tt) & 1u;
      f32x4 l;
#pragma unroll
      for (int r = 0; r < 4; ++r) l[r] = pm ? (bacc[r] + besq[r]) : NEG_MAX;
      f32x4 mx = l;
#pragma unroll
      for (int off = 1; off < 16; off <<= 1) {
#pragma unroll
        for (int r = 0; r < 4; ++r) mx[r] = fmaxf(mx[r], __shfl_xor(mx[r], off, 64));
      }
      f32x4 mn, rs;
#pragma unroll
      for (int r = 0; r < 4; ++r) {
        mn[r] = fmaxf(vm[r], mx[r]);
        p[r] = __expf(l[r] - mn[r]);
      }
      f32x4 ps = p;
#pragma unroll
      for (int off = 1; off < 16; off <<= 1) {
#pragma unroll
        for (int r = 0; r < 4; ++r) ps[r] += __shfl_xor(ps[r], off, 64);
      }
#pragma unroll
      for (int r = 0; r < 4; ++r) rs[r] = __expf(vm[r] - mn[r]);
      vs = vs * rs + ps;
      vm = mn;
      if (lane < 32) {
        float* pw = Pf + hq * 80 + j16;
        pw[0] = p[0]; pw[20] = p[1]; pw[40] = p[2]; pw[60] = p[3];
        if (j16 == 0) *(f32x4*)(Rg + hq * 4) = rs;
      }
    }

    // ---- D1: PV (VALU; thread: head hD, octet sD) -------------------------
    {
      float r = Rg[hD];
      const float* prow = Pf + hD * 20;
      f32x4 pr0 = *(const f32x4*)(prow + 0);
      f32x4 pr1 = *(const f32x4*)(prow + 4);
      f32x4 pr2 = *(const f32x4*)(prow + 8);
      f32x4 pr3 = *(const f32x4*)(prow + 12);
      const u16* vb = vwb + ((size_t)((b * 8 + hD) * 1024 + j0 + w * 16 + jh * 8)) * 32 + do4 * 8;
      f32x4 prA = jh ? pr2 : pr0, prB = jh ? pr3 : pr1;
      f32x4 sv0 = {0.f, 0.f, 0.f, 0.f}, sv1 = {0.f, 0.f, 0.f, 0.f};
#pragma unroll
      for (int x = 0; x < 8; ++x) {
        float pv = (x < 4) ? prA[x] : prB[x - 4];
        u32x4 vv = *(const u32x4*)(vb + (size_t)x * 32);
        f32x4 e0 = {asf(vv[0] << 16), asf(vv[0] & 0xffff0000u),
                    asf(vv[1] << 16), asf(vv[1] & 0xffff0000u)};
        f32x4 e1 = {asf(vv[2] << 16), asf(vv[2] & 0xffff0000u),
                    asf(vv[3] << 16), asf(vv[3] & 0xffff0000u)};
        sv0 += e0 * pv;
        sv1 += e1 * pv;
      }
      av0 = av0 * r + sv0;
      av1 = av1 * r + sv1;
    }

    // ---- D2: PE via MFMA (C rows = heads, cols = d; acc lives in C) -------
    {
      f32x4 rgv = *(const f32x4*)(Rg + (hq & 1) * 4);
      const float* pArow = Pf + (lane & 7) * 20 + (hq & 1) * 8;
      f32x4 pa0 = *(const f32x4*)(pArow);
      f32x4 pa1 = *(const f32x4*)(pArow + 4);
      u32x4 apk;
      apk[0] = cvtpk(pa0.x, pa0.y); apk[1] = cvtpk(pa0.z, pa0.w);
      apk[2] = cvtpk(pa1.x, pa1.y); apk[3] = cvtpk(pa1.z, pa1.w);
      if (hq >= 2) apk = (u32x4){0u, 0u, 0u, 0u};  // zero k=16..31 slots
      short8 pAf = __builtin_bit_cast(short8, apk);
      const float* cb = tile + (hq & 1) * 8 * TSTR + j16;
#define PE_STEP(ACC, NT) {                                                   \
      float b0 = cb[(NT)*16 + 0*TSTR], b1 = cb[(NT)*16 + 1*TSTR];            \
      float b2 = cb[(NT)*16 + 2*TSTR], b3 = cb[(NT)*16 + 3*TSTR];            \
      float b4 = cb[(NT)*16 + 4*TSTR], b5 = cb[(NT)*16 + 5*TSTR];            \
      float b6 = cb[(NT)*16 + 6*TSTR], b7 = cb[(NT)*16 + 7*TSTR];            \
      u32x4 bpk;                                                             \
      bpk[0] = cvtpk(b0, b1); bpk[1] = cvtpk(b2, b3);                        \
      bpk[2] = cvtpk(b4, b5); bpk[3] = cvtpk(b6, b7);                        \
      ACC = ACC * rgv;                                                       \
      ACC = __builtin_amdgcn_mfma_f32_16x16x32_bf16(                         \
          pAf, __builtin_bit_cast(short8, bpk), ACC, 0, 0, 0); }
      PE_STEP(acce0, 0)
      PE_STEP(acce1, 1)
      PE_STEP(acce2, 2)
      PE_STEP(acce3, 3)
#undef PE_STEP
    }

    // ---- stage next tile (after all reads; same-wave DS order) ------------
    if (pf) {
      *(f32x4*)(wdst + 0) = st0;
      *(f32x4*)(wdst + 4) = st1;
      *(f32x4*)(wdst + 8) = st2;
      *(f32x4*)(wdst + 12) = st3;
    }
  }

  // ---- epilogue: flash-merge 4 wave partials (S reused as MRG) ------------
  __syncthreads();
  float* mrg = S + w * 1040;
  if (lane < 32) {
    int h0 = hq * 4;
    if (j16 == 0) {
#pragma unroll
      for (int r = 0; r < 4; ++r) { mrg[h0 + r] = vm[r]; mrg[8 + h0 + r] = vs[r]; }
    }
#pragma unroll
    for (int r = 0; r < 4; ++r) {
      mrg[528 + (h0 + r) * 64 + 0 + j16] = acce0[r];
      mrg[528 + (h0 + r) * 64 + 16 + j16] = acce1[r];
      mrg[528 + (h0 + r) * 64 + 32 + j16] = acce2[r];
      mrg[528 + (h0 + r) * 64 + 48 + j16] = acce3[r];
    }
  }
  *(f32x4*)(mrg + 16 + jh * 256 + hD * 32 + do4 * 8) = av0;
  *(f32x4*)(mrg + 16 + jh * 256 + hD * 32 + do4 * 8 + 4) = av1;
  __syncthreads();
  {
    int h = t >> 5, d = t & 31;
    float mx = fmaxf(fmaxf(S[h], S[1040 + h]), fmaxf(S[2080 + h], S[3120 + h]));
    float ew[4];
    float ssum = 0.f, vsum = 0.f;
#pragma unroll
    for (int ww = 0; ww < 4; ++ww) {
      const float* mw = S + ww * 1040;
      ew[ww] = __expf(mw[h] - mx);
      ssum += mw[8 + h] * ew[ww];
      vsum += (mw[16 + h * 32 + d] + mw[16 + 256 + h * 32 + d]) * ew[ww];
    }
    float inv = 1.f / ssum;
    size_t obase = ((size_t)(b * 1024 + i)) * 768;
    rescat[obase + h * 32 + d] = vsum * inv;
    float e0 = 0.f, e1 = 0.f;
#pragma unroll
    for (int ww = 0; ww < 4; ++ww) {
      const float* mw = S + ww * 1040;
      e0 += mw[528 + h * 64 + d] * ew[ww];
      e1 += mw[528 + h * 64 + 32 + d] * ew[ww];
    }
    rescat[obase + 256 + h * 64 + d] = e0 * inv;
    rescat[obase + 256 + h * 64 + 32 + d] = e1 * inv;
  }
}

// ---------------- kernel C: output projection ----------------------------
__global__ __launch_bounds__(256) void out_proj(
    const float* __restrict__ rescat, const float* __restrict__ Wo,
    const float* __restrict__ bo, float* __restrict__ out) {
  __shared__ __align__(16) float xs[8 * 768];
  int t = threadIdx.x;
  int row0 = blockIdx.x * 8;
#pragma unroll
  for (int p = 0; p < 6; ++p) {
    int f = p * 256 + t;
    *(f32x4*)(&xs[f * 4]) = *(const f32x4*)(rescat + (size_t)row0 * 768 + f * 4);
  }
  __syncthreads();
  float acc[8];
#pragma unroll
  for (int r = 0; r < 8; ++r) acc[r] = 0.f;
  for (int c = 0; c < 768; ++c) {
    float w = Wo[c * 256 + t];
#pragma unroll
    for (int r = 0; r < 8; ++r) acc[r] += xs[r * 768 + c] * w;
  }
  float bias = bo[t];
#pragma unroll
  for (int r = 0; r < 8; ++r)
    out[(size_t)(row0 + r) * 256 + t] = acc[r] + bias;
}

// ---------------- launch ---------------------------------------------------
extern "C" void kernel_launch(void* const* d_in, const int* in_sizes, int n_in,
                              void* d_out, int out_size, void* d_ws, size_t ws_size,
                              hipStream_t stream) {
  const float* node = (const float*)d_in[0];
  const float* edge = (const float*)d_in[1];
  const unsigned char* mask = (const unsigned char*)d_in[2];
  const float* Wq = (const float*)d_in[3];
  const float* Wk = (const float*)d_in[4];
  const float* Wv = (const float*)d_in[5];
  const float* We = (const float*)d_in[6];
  const float* be = (const float*)d_in[7];
  const float* Wo = (const float*)d_in[8];
  const float* bo = (const float*)d_in[9];

  float* ws = (float*)d_ws;
  float* qw = ws;                              // 524288 f32
  u16* kwb = (u16*)(ws + 524288);              // 524288 bf16
  u16* vwb = kwb + 524288;                     // 524288 bf16
  float* rescat = ws + 1048576;                // 1572864 f32
  float* mask_f = ws + 2621440;                // 2048 f32

  hipLaunchKernelGGL(mask_norm, dim3(1), dim3(256), 0, stream, mask, mask_f);
  hipLaunchKernelGGL(qkv_rope, dim3(256), dim3(256), 0, stream,
                     node, Wq, Wk, Wv, qw, kwb, vwb);
  hipLaunchKernelGGL(attn_fused, dim3(2048), dim3(256), 0, stream,
                     edge, qw, kwb, vwb, We, be, mask_f, rescat);
  hipLaunchKernelGGL(out_proj, dim3(256), dim3(256), 0, stream,
                     rescat, Wo, bo, (float*)d_out);
}